// Round 9
// baseline (710.743 us; speedup 1.0000x reference)
//
#include <hip/hip_runtime.h>
#include <math.h>

#define BB 2
#define NN 20000
#define EE 100000
#define DD 3
#define KK 128
#define CC 128
#define LL 3
#define FCC 128
#define GJ (DD*CC)    // 384
#define KR 768        // stacked contraction: 128 bc + 128 bs + 128 h + 384 g
#define NP 20096      // padded N: 157 tiles * 128
#define NCHK 157      // 128-row chunks
#define G1CH 79       // gemm1 split-k chunks (256 n each)
#define G1N 256

typedef __attribute__((ext_vector_type(8))) short bf16x8;
typedef __attribute__((ext_vector_type(4))) float f32x4;

__device__ inline unsigned short f2bf(float f) {
  unsigned int u = __float_as_uint(f);
  u += 0x7fffu + ((u >> 16) & 1u);
  return (unsigned short)(u >> 16);
}
__device__ inline float bf2f(unsigned short u) {
  return __uint_as_float(((unsigned int)u) << 16);
}

// ---- scratch (device globals) ----
__device__ float d_nw[BB*NN];
__device__ __align__(16) unsigned short d_stackT[(size_t)BB*NP*KR]; // [b][n][r] bf16: 0 bc,128 bs,256 h,384 g
__device__ __align__(16) unsigned short d_bcT[(size_t)BB*KK*NP];    // [b][k][n] bf16, pad-zeroed
__device__ __align__(16) unsigned short d_bsT[(size_t)BB*KK*NP];
__device__ __align__(16) unsigned short d_hTwT[(size_t)BB*CC*NP];   // [b][c][n] bf16 = h*nw, pad-zeroed
__device__ __align__(16) float d_hnewT[(size_t)BB*NP*CC];   // h [b][n][c] fp32
__device__ __align__(16) float d_uT[(size_t)BB*NP*FCC];     // fc1 out [b][n][o2]
__device__ __align__(16) unsigned short d_Amatb[BB*CC*KR];  // [b][o][r] bf16
__device__ __align__(16) unsigned short d_fc1wb[FCC*CC];    // [o2][c] bf16
__device__ __align__(16) float d_part[(size_t)BB*G1CH*2*128*128];   // [b][chunk][arr][c*128+k]
__device__ float d_xc[BB*CC*KK];
__device__ float d_xs[BB*CC*KK];
__device__ float d_x0p[BB*NCHK*CC];
__device__ float d_fcv[BB*CC*KK];
__device__ float d_fsv[BB*CC*KK];
__device__ float d_bias[BB*CC];
// CSR
__device__ int d_cnt[BB*NN];
__device__ int d_cursor[BB*NN];
__device__ int d_off[BB*(NN+1)];
__device__ __align__(16) float4 d_erec[(size_t)BB*EE];      // {dst_bits, w0, w1, w2}

// ---- basis -> stackT bc/bs slabs (bf16) ----
__global__ __launch_bounds__(128) void k_basis(const float* __restrict__ nodes,
                                               const float* __restrict__ nodew,
                                               const float* __restrict__ modes,
                                               const float* __restrict__ spL) {
  int bn = blockIdx.x;            // b*NN + n
  int k  = threadIdx.x;
  int b = bn / NN, n = bn % NN;
  float x0 = nodes[bn*3+0], x1 = nodes[bn*3+1], x2 = nodes[bn*3+2];
  float tmp = x0*modes[k*3+0]*spL[0] + x1*modes[k*3+1]*spL[1] + x2*modes[k*3+2]*spL[2];
  float cv = cosf(tmp), sv = sinf(tmp);
  size_t row = (size_t)(b*NP + n);
  d_stackT[row*KR + k]       = f2bf(cv);
  d_stackT[row*KR + 128 + k] = f2bf(sv);
  if (k == 0) d_nw[bn] = nodew[bn];
}

// ---- transpose stackT bc/bs slabs -> bcT/bsT [k][n] bf16 (once; zero-pads n>=NN) ----
__global__ __launch_bounds__(256) void k_basisT() {
  __shared__ unsigned short t1[32][136];
  __shared__ unsigned short t2[32][136];
  int blk = blockIdx.x;          // 628 * BB
  int nt = blk % 628, b = blk / 628;
  int n0 = nt*32;
  int tid = threadIdx.x;
  int kl = tid & 127, ng = tid >> 7;
  for (int nn = ng; nn < 32; nn += 2) {
    int n = n0 + nn;
    unsigned short cv = 0, sv = 0;
    if (n < NN) {
      const unsigned short* sp = d_stackT + ((size_t)(b*NP + n))*KR;
      cv = sp[kl]; sv = sp[128 + kl];
    }
    t1[nn][kl] = cv;
    t2[nn][kl] = sv;
  }
  __syncthreads();
  int nl = tid & 31, kg = tid >> 5;
  for (int k = kg; k < 128; k += 8) {
    d_bcT[((size_t)(b*KK + k))*NP + n0 + nl] = t1[nl][k];
    d_bsT[((size_t)(b*KK + k))*NP + n0 + nl] = t2[nl][k];
  }
}

// ---- CSR build ----
__global__ __launch_bounds__(256) void k_csr_zero() {
  int tid = blockIdx.x*256 + threadIdx.x;
  if (tid < BB*NN) { d_cnt[tid] = 0; d_cursor[tid] = 0; }
}

__global__ __launch_bounds__(256) void k_csr_count(const int* __restrict__ edges) {
  int e = blockIdx.x*256 + threadIdx.x;
  if (e >= BB*EE) return;
  int b = e / EE;
  int src = edges[e*2 + 0];
  atomicAdd(&d_cnt[b*NN + src], 1);
}

__global__ __launch_bounds__(1024) void k_csr_scan() {
  int b = blockIdx.x;
  __shared__ int sdata[1024];
  __shared__ int carry_s;
  int tid = threadIdx.x;
  if (tid == 0) carry_s = 0;
  __syncthreads();
  for (int chunk = 0; chunk < 20; ++chunk) {
    int i = chunk*1024 + tid;
    int v = (i < NN) ? d_cnt[b*NN + i] : 0;
    sdata[tid] = v;
    __syncthreads();
    for (int s = 1; s < 1024; s <<= 1) {
      int tv = (tid >= s) ? sdata[tid - s] : 0;
      __syncthreads();
      sdata[tid] += tv;
      __syncthreads();
    }
    int excl = carry_s + sdata[tid] - v;
    if (i < NN) d_off[b*(NN+1) + i] = excl;
    __syncthreads();
    if (tid == 1023) carry_s += sdata[1023];
    __syncthreads();
  }
  if (tid == 0) d_off[b*(NN+1) + NN] = carry_s;
}

// ---- scatter: build packed edge records {dst, w0, w1, w2} ----
__global__ __launch_bounds__(256) void k_csr_scatter(const int* __restrict__ edges,
                                                     const float* __restrict__ egw) {
  int e = blockIdx.x*256 + threadIdx.x;
  if (e >= BB*EE) return;
  int b = e / EE;
  int src = edges[e*2 + 0];
  int dst = edges[e*2 + 1];
  int pos = atomicAdd(&d_cursor[b*NN + src], 1);
  d_erec[(size_t)b*EE + d_off[b*(NN+1) + src] + pos] =
      make_float4(__int_as_float(dst), egw[e*3+0], egw[e*3+1], egw[e*3+2]);
}

// ---- fc0 -> hnewT + stackT h slab ----
__global__ __launch_bounds__(256) void k_h0(const float* __restrict__ x,
                                            const float* __restrict__ t,
                                            const float* __restrict__ w,
                                            const float* __restrict__ bias) {
  int tid = blockIdx.x*256 + threadIdx.x;   // (b*NN+n)*CC + c
  int c = tid & 127;
  int bn = tid >> 7;
  int b = bn / NN, n = bn % NN;
  const float* xv = x + bn*3;
  float acc = bias[c] + xv[0]*w[c] + xv[1]*w[CC+c] + xv[2]*w[2*CC+c]
            + t[bn]*w[3*CC+c];
  size_t row = (size_t)(b*NP + n);
  d_hnewT[row*CC + c] = acc;
  d_stackT[row*KR + 256 + c] = f2bf(acc);
}

// ---- layer-0 hTwT: hnewT [n][c] * nw -> bf16 [c][n], zero-pads ----
__global__ __launch_bounds__(256) void k_hT0() {
  __shared__ unsigned short t[128][136];
  int chunk = blockIdx.x;   // NCHK
  int b = blockIdx.y;
  int n0 = chunk*128;
  int tid = threadIdx.x;
  int cl = tid & 127, ng = tid >> 7;
  for (int nn = ng; nn < 128; nn += 2) {
    int n = n0 + nn;
    unsigned short v = 0;
    if (n < NN) v = f2bf(d_hnewT[((size_t)(b*NP + n))*CC + cl] * d_nw[b*NN + n]);
    t[nn][cl] = v;
  }
  __syncthreads();
  int nl = tid & 31, cg = tid >> 5;
  for (int c = cg; c < 128; c += 8)
    for (int nn2 = 0; nn2 < 128; nn2 += 32)
      d_hTwT[((size_t)(b*CC + c))*NP + n0 + nn2 + nl] = t[nn2 + nl][c];
}

// ---- gemm1 MFMA: part[c][k] += sum_n hTwT[c][n]*bcT/bsT[k][n] ----
__global__ __launch_bounds__(256) void k_gemm1m() {
  __shared__ unsigned short Bsh[2][128][40];
  int chunk = blockIdx.x;   // G1CH
  int b = blockIdx.y;
  int tid = threadIdx.x, lane = tid & 63, wid = tid >> 6;
  int q = lane >> 4, m = lane & 15;
  f32x4 accC[2][8], accS[2][8];
  #pragma unroll
  for (int i = 0; i < 2; i++)
    #pragma unroll
    for (int j = 0; j < 8; j++) { accC[i][j] = (f32x4){0.f,0.f,0.f,0.f}; accS[i][j] = (f32x4){0.f,0.f,0.f,0.f}; }
  const unsigned short* Ab = d_hTwT + (size_t)b*CC*NP;
  const unsigned short* Bcp = d_bcT + (size_t)b*KK*NP;
  const unsigned short* Bsp = d_bsT + (size_t)b*KK*NP;
  int n0 = chunk*G1N;
  for (int s = 0; s < G1N/32; s++) {
    int nb = n0 + s*32;
    if (nb >= NP) break;
    __syncthreads();
    {
      int arr = tid >> 7, row = tid & 127;
      const unsigned short* src = (arr ? Bsp : Bcp) + (size_t)row*NP + nb;
      unsigned short* dr = &Bsh[arr][row][0];
      *(uint4*)&dr[0]  = *(const uint4*)&src[0];
      *(uint4*)&dr[8]  = *(const uint4*)&src[8];
      *(uint4*)&dr[16] = *(const uint4*)&src[16];
      *(uint4*)&dr[24] = *(const uint4*)&src[24];
    }
    __syncthreads();
    bf16x8 a0 = *(const bf16x8*)(Ab + (size_t)(wid*32 + m)*NP + nb + q*8);
    bf16x8 a1 = *(const bf16x8*)(Ab + (size_t)(wid*32 + 16 + m)*NP + nb + q*8);
    #pragma unroll
    for (int kt = 0; kt < 8; kt++) {
      bf16x8 bcf = *(const bf16x8*)&Bsh[0][kt*16 + m][q*8];
      bf16x8 bsf = *(const bf16x8*)&Bsh[1][kt*16 + m][q*8];
      accC[0][kt] = __builtin_amdgcn_mfma_f32_16x16x32_bf16(a0, bcf, accC[0][kt], 0, 0, 0);
      accC[1][kt] = __builtin_amdgcn_mfma_f32_16x16x32_bf16(a1, bcf, accC[1][kt], 0, 0, 0);
      accS[0][kt] = __builtin_amdgcn_mfma_f32_16x16x32_bf16(a0, bsf, accS[0][kt], 0, 0, 0);
      accS[1][kt] = __builtin_amdgcn_mfma_f32_16x16x32_bf16(a1, bsf, accS[1][kt], 0, 0, 0);
    }
  }
  float* base = d_part + (((size_t)b*G1CH + chunk)*2)*16384;
  #pragma unroll
  for (int mt = 0; mt < 2; mt++)
    #pragma unroll
    for (int kt = 0; kt < 8; kt++)
      #pragma unroll
      for (int r = 0; r < 4; r++) {
        int c = wid*32 + mt*16 + q*4 + r;
        int k = kt*16 + m;
        base[c*128 + k]         =  accC[mt][kt][r];
        base[16384 + c*128 + k] = -accS[mt][kt][r];   // xs = -sum
      }
}

// ---- reduce split-k partials -> xc, xs ----
__global__ __launch_bounds__(256) void k_reduce1() {
  int tid = blockIdx.x*256 + threadIdx.x;   // BB*2*128*128 = 65536
  int k = tid & 127;
  int c = (tid >> 7) & 127;
  int arr = (tid >> 14) & 1;
  int b = tid >> 15;
  const float* p = d_part + (((size_t)b*G1CH)*2 + arr)*16384 + c*128 + k;
  float acc = 0.f;
  for (int ch = 0; ch < G1CH; ch++) acc += p[(size_t)ch*2*16384];
  if (arr == 0) d_xc[(b*CC + c)*KK + k] = acc;
  else          d_xs[(b*CC + c)*KK + k] = acc;
}

// ---- x0 partials from hTwT bf16 ----
__global__ __launch_bounds__(256) void k_x0() {
  int chunk = blockIdx.x;   // NCHK
  int b = blockIdx.y;
  int tid = threadIdx.x;
  int c = tid >> 1, half = tid & 1;
  const unsigned short* p = d_hTwT + ((size_t)(b*CC + c))*NP + chunk*128 + half*64;
  float acc = 0.f;
  #pragma unroll
  for (int i = 0; i < 8; i++) {
    ushort4 v0 = *(const ushort4*)&p[i*8];
    ushort4 v1 = *(const ushort4*)&p[i*8 + 4];
    acc += bf2f(v0.x) + bf2f(v0.y) + bf2f(v0.z) + bf2f(v0.w)
         + bf2f(v1.x) + bf2f(v1.y) + bf2f(v1.z) + bf2f(v1.w);
  }
  __shared__ float red[128][2];
  red[c][half] = acc;
  __syncthreads();
  if (half == 0) d_x0p[(b*NCHK + chunk)*CC + c] = red[c][0] + red[c][1];
}

// ---- spectral mix per k ----
__global__ __launch_bounds__(128) void k_spec(const float* __restrict__ Wc,
                                              const float* __restrict__ Ws, int l) {
  int b = blockIdx.x >> 7;
  int o = blockIdx.x & 127;
  int k = threadIdx.x;
  const float* wcp = Wc + ((size_t)(l*CC)*CC + o)*KK + k;
  const float* wsp = Ws + ((size_t)(l*CC)*CC + o)*KK + k;
  float fc = 0.f, fs = 0.f;
  for (int i = 0; i < CC; i++) {
    float xcv = d_xc[(b*CC + i)*KK + k];
    float xsv = d_xs[(b*CC + i)*KK + k];
    float wcv = wcp[(size_t)i*CC*KK];
    float wsv = wsp[(size_t)i*CC*KK];
    fc += xcv*wcv - xsv*wsv;
    fs += xsv*wcv + xcv*wsv;
  }
  d_fcv[(b*CC + o)*KK + k] = fc;
  d_fsv[(b*CC + o)*KK + k] = fs;
}

// ---- f0 + full bias ----
__global__ __launch_bounds__(128) void k_f0(const float* __restrict__ W0,
                                            const float* __restrict__ wsb,
                                            const float* __restrict__ gwsb, int l) {
  int b = blockIdx.x;
  int o = threadIdx.x;
  __shared__ float sx[CC];
  float xv = 0.f;
  for (int p = 0; p < NCHK; p++) xv += d_x0p[(b*NCHK + p)*CC + o];
  sx[o] = xv;
  __syncthreads();
  float acc = 0.f;
  for (int i = 0; i < CC; i++) acc += sx[i]*W0[(l*CC + i)*CC + o];
  d_bias[b*CC + o] = acc + wsb[l*CC + o] + gwsb[l*CC + o];
}

// ---- build A matrix [b][o][r] bf16 ----
__global__ __launch_bounds__(128) void k_buildAb(const float* __restrict__ wsw,
                                                 const float* __restrict__ gwsw, int l) {
  int bo = blockIdx.x;
  int b = bo >> 7, o = bo & 127;
  int t = threadIdx.x;
  unsigned short* dst = d_Amatb + (size_t)bo*KR;
  dst[t]       = f2bf( 2.f*d_fcv[(size_t)bo*KK + t]);
  dst[128 + t] = f2bf(-2.f*d_fsv[(size_t)bo*KK + t]);
  dst[256 + t] = f2bf(wsw[(l*CC + o)*CC + t]);
  #pragma unroll
  for (int j = 0; j < 3; j++)
    dst[384 + j*128 + t] = f2bf(gwsw[(size_t)(l*CC + o)*GJ + j*128 + t]);
}

// ---- fc1w transpose to [o2][c] bf16 ----
__global__ __launch_bounds__(128) void k_fc1w(const float* __restrict__ fc1w) {
  int c = blockIdx.x;
  int o2 = threadIdx.x;
  d_fc1wb[o2*CC + c] = f2bf(fc1w[c*FCC + o2]);
}

// ---- CSR edge gradient via packed records -> stackT g slab ----
__global__ __launch_bounds__(128) void k_grad_csr() {
  int bn = blockIdx.x;            // b*NN + n
  int b = bn / NN, n = bn % NN;
  int c = threadIdx.x;
  int beg = d_off[b*(NN+1) + n];
  int end = d_off[b*(NN+1) + n + 1];
  const float4* rp = d_erec + (size_t)b*EE;
  const float* hb = d_hnewT + (size_t)b*NP*CC + c;
  float a0 = 0.f, a1 = 0.f, a2 = 0.f;
  float sw0 = 0.f, sw1 = 0.f, sw2 = 0.f;
  int p = beg;
  for (; p + 2 <= end; p += 2) {
    float4 r1 = rp[p], r2 = rp[p+1];
    float f1 = hb[(size_t)__float_as_int(r1.x)*CC];
    float f2 = hb[(size_t)__float_as_int(r2.x)*CC];
    a0 += r1.y*f1 + r2.y*f2;
    a1 += r1.z*f1 + r2.z*f2;
    a2 += r1.w*f1 + r2.w*f2;
    sw0 += r1.y + r2.y; sw1 += r1.z + r2.z; sw2 += r1.w + r2.w;
  }
  if (p < end) {
    float4 r1 = rp[p];
    float f1 = hb[(size_t)__float_as_int(r1.x)*CC];
    a0 += r1.y*f1; a1 += r1.z*f1; a2 += r1.w*f1;
    sw0 += r1.y; sw1 += r1.z; sw2 += r1.w;
  }
  float fs = d_hnewT[((size_t)(b*NP + n))*CC + c];
  a0 -= sw0*fs; a1 -= sw1*fs; a2 -= sw2*fs;
  unsigned short* gp = d_stackT + ((size_t)(b*NP + n))*KR + 384;
  gp[c]        = f2bf(a0/(1.f + fabsf(a0)));
  gp[CC + c]   = f2bf(a1/(1.f + fabsf(a1)));
  gp[2*CC + c] = f2bf(a2/(1.f + fabsf(a2)));
}

// ---- MFMA GEMM v3: direct global->register, no LDS, no barriers ----
// Out[b][n][o] = sum_k stackT[b][n][koff+k] * W[b?][o][k] + bias[o]
// 64n x 128o per block (4 waves x 16n), register ping-pong over 32-k chunks.
__global__ __launch_bounds__(256) void k_mfma(int koff, int K,
                                              const unsigned short* __restrict__ W, size_t wstride,
                                              float* __restrict__ Out,
                                              const float* __restrict__ bias, int bias_stride,
                                              int gelu, int aux) {
  int b = blockIdx.z;
  int n_base = blockIdx.x*64;
  int tid = threadIdx.x;
  int lane = tid & 63, wid = tid >> 6;
  int q = lane >> 4, m = lane & 15;

  f32x4 acc[8];
  #pragma unroll
  for (int j = 0; j < 8; j++) acc[j] = (f32x4){0.f,0.f,0.f,0.f};

  const unsigned short* Arow = d_stackT + (size_t)b*NP*KR + koff
                             + (size_t)(n_base + wid*16 + m)*KR + q*8;
  const unsigned short* Brow = W + (size_t)b*wstride + (size_t)m*K + q*8;

  bf16x8 aP, bP[8], aQ, bQ[8];
  aP = *(const bf16x8*)Arow;
  #pragma unroll
  for (int ot = 0; ot < 8; ot++) bP[ot] = *(const bf16x8*)(Brow + (size_t)(ot*16)*K);

  int nch = K >> 5;   // 32-k chunks (even: 24 or 4)
  for (int ch = 0; ch < nch; ch += 2) {
    int k1 = (ch + 1)*32;
    aQ = *(const bf16x8*)(Arow + k1);
    #pragma unroll
    for (int ot = 0; ot < 8; ot++) bQ[ot] = *(const bf16x8*)(Brow + (size_t)(ot*16)*K + k1);
    #pragma unroll
    for (int ot = 0; ot < 8; ot++)
      acc[ot] = __builtin_amdgcn_mfma_f32_16x16x32_bf16(aP, bP[ot], acc[ot], 0, 0, 0);
    if (ch + 2 < nch) {
      int k2 = (ch + 2)*32;
      aP = *(const bf16x8*)(Arow + k2);
      #pragma unroll
      for (int ot = 0; ot < 8; ot++) bP[ot] = *(const bf16x8*)(Brow + (size_t)(ot*16)*K + k2);
    }
    #pragma unroll
    for (int ot = 0; ot < 8; ot++)
      acc[ot] = __builtin_amdgcn_mfma_f32_16x16x32_bf16(aQ, bQ[ot], acc[ot], 0, 0, 0);
  }

  const float* bp = bias + (size_t)b*bias_stride;
  int nb4 = n_base + wid*16 + q*4;
  float nw4[4];
  #pragma unroll
  for (int r = 0; r < 4; r++)
    nw4[r] = (aux && nb4 + r < NN) ? d_nw[b*NN + nb4 + r] : 0.f;
  #pragma unroll
  for (int ot = 0; ot < 8; ot++) {
    int o = ot*16 + m;
    float bvv = bp[o];
    float vals[4];
    #pragma unroll
    for (int r = 0; r < 4; r++) {
      float v = acc[ot][r] + bvv;
      if (gelu) v = 0.5f*v*(1.f + erff(v*0.70710678118f));
      vals[r] = v;
      Out[((size_t)(b*NP + nb4 + r))*128 + o] = v;
      if (aux && nb4 + r < NN)
        d_stackT[((size_t)(b*NP + nb4 + r))*KR + 256 + o] = f2bf(v);
    }
    if (aux) {
      ushort4 pk;
      pk.x = f2bf(vals[0]*nw4[0]);
      pk.y = f2bf(vals[1]*nw4[1]);
      pk.z = f2bf(vals[2]*nw4[2]);
      pk.w = f2bf(vals[3]*nw4[3]);
      *(ushort4*)&d_hTwT[((size_t)(b*CC + o))*NP + nb4] = pk;
    }
  }
}

// ---- fc2 + residual; u = d_uT [b][n][o2] ----
__global__ __launch_bounds__(256) void k_out(const float* __restrict__ x,
                                             const float* __restrict__ t,
                                             const float* __restrict__ fc2w,
                                             const float* __restrict__ fc2b,
                                             float* __restrict__ out) {
  int tid = blockIdx.x*256 + threadIdx.x;
  if (tid >= BB*NN) return;
  int b = tid / NN, n = tid % NN;
  const float* up = d_uT + ((size_t)(b*NP + n))*FCC;
  float a0 = fc2b[0], a1 = fc2b[1], a2v = fc2b[2];
  #pragma unroll 4
  for (int o2 = 0; o2 < FCC; o2 += 4) {
    float4 uv = *(const float4*)&up[o2];
    a0  += uv.x*fc2w[(o2+0)*3+0] + uv.y*fc2w[(o2+1)*3+0] + uv.z*fc2w[(o2+2)*3+0] + uv.w*fc2w[(o2+3)*3+0];
    a1  += uv.x*fc2w[(o2+0)*3+1] + uv.y*fc2w[(o2+1)*3+1] + uv.z*fc2w[(o2+2)*3+1] + uv.w*fc2w[(o2+3)*3+1];
    a2v += uv.x*fc2w[(o2+0)*3+2] + uv.y*fc2w[(o2+1)*3+2] + uv.z*fc2w[(o2+2)*3+2] + uv.w*fc2w[(o2+3)*3+2];
  }
  float tv = t[tid];
  out[tid*3 + 0] = x[tid*3 + 0] + tv*a0;
  out[tid*3 + 1] = x[tid*3 + 1] + tv*a1;
  out[tid*3 + 2] = x[tid*3 + 2] + tv*a2v;
}

extern "C" void kernel_launch(void* const* d_in, const int* in_sizes, int n_in,
                              void* d_out, int out_size, void* d_ws, size_t ws_size,
                              hipStream_t stream) {
  const float* x     = (const float*)d_in[0];
  const float* t     = (const float*)d_in[1];
  const float* nodes = (const float*)d_in[3];
  const float* nodew = (const float*)d_in[4];
  const int*   edges = (const int*)d_in[5];
  const float* egw   = (const float*)d_in[6];
  const float* modes = (const float*)d_in[7];
  const float* spL   = (const float*)d_in[8];
  const float* fc0w  = (const float*)d_in[9];
  const float* fc0b  = (const float*)d_in[10];
  const float* Wc    = (const float*)d_in[11];
  const float* Ws    = (const float*)d_in[12];
  const float* W0    = (const float*)d_in[13];
  const float* wsw   = (const float*)d_in[14];
  const float* wsb   = (const float*)d_in[15];
  const float* gwsw  = (const float*)d_in[16];
  const float* gwsb  = (const float*)d_in[17];
  const float* fc1w  = (const float*)d_in[18];
  const float* fc1b  = (const float*)d_in[19];
  const float* fc2w  = (const float*)d_in[20];
  const float* fc2b  = (const float*)d_in[21];
  float* out = (float*)d_out;

  unsigned short* d_Amatb_p; hipGetSymbolAddress((void**)&d_Amatb_p, HIP_SYMBOL(d_Amatb));
  unsigned short* d_fc1wb_p; hipGetSymbolAddress((void**)&d_fc1wb_p, HIP_SYMBOL(d_fc1wb));
  float* d_hnewT_p; hipGetSymbolAddress((void**)&d_hnewT_p, HIP_SYMBOL(d_hnewT));
  float* d_uT_p;    hipGetSymbolAddress((void**)&d_uT_p,    HIP_SYMBOL(d_uT));
  float* d_bias_p;  hipGetSymbolAddress((void**)&d_bias_p,  HIP_SYMBOL(d_bias));

  hipLaunchKernelGGL(k_basis, dim3(BB*NN), dim3(128), 0, stream, nodes, nodew, modes, spL);
  hipLaunchKernelGGL(k_basisT, dim3(628*BB), dim3(256), 0, stream);
  hipLaunchKernelGGL(k_h0, dim3(BB*NN*CC/256), dim3(256), 0, stream, x, t, fc0w, fc0b);
  hipLaunchKernelGGL(k_hT0, dim3(NCHK, BB), dim3(256), 0, stream);
  hipLaunchKernelGGL(k_fc1w, dim3(CC), dim3(FCC), 0, stream, fc1w);
  // CSR build (once; edges constant across layers)
  hipLaunchKernelGGL(k_csr_zero, dim3((BB*NN + 255)/256), dim3(256), 0, stream);
  hipLaunchKernelGGL(k_csr_count, dim3((BB*EE + 255)/256), dim3(256), 0, stream, edges);
  hipLaunchKernelGGL(k_csr_scan, dim3(BB), dim3(1024), 0, stream);
  hipLaunchKernelGGL(k_csr_scatter, dim3((BB*EE + 255)/256), dim3(256), 0, stream, edges, egw);

  for (int l = 0; l < LL; l++) {
    hipLaunchKernelGGL(k_gemm1m, dim3(G1CH, BB), dim3(256), 0, stream);
    hipLaunchKernelGGL(k_reduce1, dim3(256), dim3(256), 0, stream);
    hipLaunchKernelGGL(k_x0, dim3(NCHK, BB), dim3(256), 0, stream);
    hipLaunchKernelGGL(k_spec, dim3(BB*CC), dim3(128), 0, stream, Wc, Ws, l);
    hipLaunchKernelGGL(k_f0, dim3(BB), dim3(CC), 0, stream, W0, wsb, gwsb, l);
    hipLaunchKernelGGL(k_buildAb, dim3(BB*CC), dim3(128), 0, stream, wsw, gwsw, l);
    hipLaunchKernelGGL(k_grad_csr, dim3(BB*NN), dim3(128), 0, stream);
    hipLaunchKernelGGL(k_mfma, dim3(NP/64, 1, BB), dim3(256), 0, stream,
                       0, KR, d_Amatb_p, (size_t)CC*KR, d_hnewT_p, d_bias_p, CC,
                       (l != LL-1) ? 1 : 0, 1);
  }

  // fc1 via MFMA on the h slab
  hipLaunchKernelGGL(k_mfma, dim3(NP/64, 1, BB), dim3(256), 0, stream,
                     256, CC, d_fc1wb_p, (size_t)0, d_uT_p, fc1b, 0, 1, 0);
  hipLaunchKernelGGL(k_out, dim3((BB*NN + 255)/256), dim3(256), 0, stream, x, t, fc2w, fc2b, out);
}

// Round 10
// 588.263 us; speedup vs baseline: 1.2082x; 1.2082x over previous
//
#include <hip/hip_runtime.h>
#include <math.h>

#define BB 2
#define NN 20000
#define EE 100000
#define DD 3
#define KK 128
#define CC 128
#define LL 3
#define FCC 128
#define GJ (DD*CC)    // 384
#define KR 768        // stacked contraction: 128 bc + 128 bs + 128 h + 384 g
#define NP 20096      // padded N: 157 tiles * 128
#define NCHK 157      // 128-row chunks
#define G1CH 79       // gemm1 split-k chunks (256 n each)
#define G1N 256

typedef __attribute__((ext_vector_type(8))) short bf16x8;
typedef __attribute__((ext_vector_type(4))) float f32x4;

__device__ inline unsigned short f2bf(float f) {
  unsigned int u = __float_as_uint(f);
  u += 0x7fffu + ((u >> 16) & 1u);
  return (unsigned short)(u >> 16);
}
__device__ inline float bf2f(unsigned short u) {
  return __uint_as_float(((unsigned int)u) << 16);
}

// ---- scratch (device globals) ----
__device__ float d_nw[BB*NN];
__device__ __align__(16) unsigned short d_stackT[(size_t)BB*NP*KR]; // [b][n][r] bf16: 0 bc,128 bs,256 h,384 g
__device__ __align__(16) unsigned short d_bcT[(size_t)BB*KK*NP];    // [b][k][n] bf16, pad-zeroed
__device__ __align__(16) unsigned short d_bsT[(size_t)BB*KK*NP];
__device__ __align__(16) unsigned short d_hTwT[(size_t)BB*CC*NP];   // [b][c][n] bf16 = h*nw, pad-zeroed
__device__ __align__(16) float d_hnewT[(size_t)BB*NP*CC];   // h [b][n][c] fp32
__device__ __align__(16) float d_uT[(size_t)BB*NP*FCC];     // fc1 out [b][n][o2]
__device__ __align__(16) unsigned short d_Amatb[BB*CC*KR];  // [b][o][r] bf16
__device__ __align__(16) unsigned short d_fc1wb[FCC*CC];    // [o2][c] bf16
__device__ __align__(16) float d_part[(size_t)BB*G1CH*2*128*128];   // [b][chunk][arr][c*128+k]
__device__ float d_xc[BB*CC*KK];
__device__ float d_xs[BB*CC*KK];
__device__ float d_x0p[BB*NCHK*CC];
__device__ float d_fcv[BB*CC*KK];
__device__ float d_fsv[BB*CC*KK];
__device__ float d_bias[BB*CC];
// CSR
__device__ int d_cnt[BB*NN];
__device__ int d_cursor[BB*NN];
__device__ int d_off[BB*(NN+1)];
__device__ __align__(16) float4 d_erec[(size_t)BB*EE];      // {dst_bits, w0, w1, w2}

// ---- basis -> stackT bc/bs slabs (bf16) ----
__global__ __launch_bounds__(128) void k_basis(const float* __restrict__ nodes,
                                               const float* __restrict__ nodew,
                                               const float* __restrict__ modes,
                                               const float* __restrict__ spL) {
  int bn = blockIdx.x;            // b*NN + n
  int k  = threadIdx.x;
  int b = bn / NN, n = bn % NN;
  float x0 = nodes[bn*3+0], x1 = nodes[bn*3+1], x2 = nodes[bn*3+2];
  float tmp = x0*modes[k*3+0]*spL[0] + x1*modes[k*3+1]*spL[1] + x2*modes[k*3+2]*spL[2];
  float cv = cosf(tmp), sv = sinf(tmp);
  size_t row = (size_t)(b*NP + n);
  d_stackT[row*KR + k]       = f2bf(cv);
  d_stackT[row*KR + 128 + k] = f2bf(sv);
  if (k == 0) d_nw[bn] = nodew[bn];
}

// ---- transpose stackT bc/bs slabs -> bcT/bsT [k][n] bf16 (once; zero-pads n>=NN) ----
__global__ __launch_bounds__(256) void k_basisT() {
  __shared__ unsigned short t1[32][136];
  __shared__ unsigned short t2[32][136];
  int blk = blockIdx.x;          // 628 * BB
  int nt = blk % 628, b = blk / 628;
  int n0 = nt*32;
  int tid = threadIdx.x;
  int kl = tid & 127, ng = tid >> 7;
  for (int nn = ng; nn < 32; nn += 2) {
    int n = n0 + nn;
    unsigned short cv = 0, sv = 0;
    if (n < NN) {
      const unsigned short* sp = d_stackT + ((size_t)(b*NP + n))*KR;
      cv = sp[kl]; sv = sp[128 + kl];
    }
    t1[nn][kl] = cv;
    t2[nn][kl] = sv;
  }
  __syncthreads();
  int nl = tid & 31, kg = tid >> 5;
  for (int k = kg; k < 128; k += 8) {
    d_bcT[((size_t)(b*KK + k))*NP + n0 + nl] = t1[nl][k];
    d_bsT[((size_t)(b*KK + k))*NP + n0 + nl] = t2[nl][k];
  }
}

// ---- CSR build ----
__global__ __launch_bounds__(256) void k_csr_zero() {
  int tid = blockIdx.x*256 + threadIdx.x;
  if (tid < BB*NN) { d_cnt[tid] = 0; d_cursor[tid] = 0; }
}

__global__ __launch_bounds__(256) void k_csr_count(const int* __restrict__ edges) {
  int e = blockIdx.x*256 + threadIdx.x;
  if (e >= BB*EE) return;
  int b = e / EE;
  int src = edges[e*2 + 0];
  atomicAdd(&d_cnt[b*NN + src], 1);
}

__global__ __launch_bounds__(1024) void k_csr_scan() {
  int b = blockIdx.x;
  __shared__ int sdata[1024];
  __shared__ int carry_s;
  int tid = threadIdx.x;
  if (tid == 0) carry_s = 0;
  __syncthreads();
  for (int chunk = 0; chunk < 20; ++chunk) {
    int i = chunk*1024 + tid;
    int v = (i < NN) ? d_cnt[b*NN + i] : 0;
    sdata[tid] = v;
    __syncthreads();
    for (int s = 1; s < 1024; s <<= 1) {
      int tv = (tid >= s) ? sdata[tid - s] : 0;
      __syncthreads();
      sdata[tid] += tv;
      __syncthreads();
    }
    int excl = carry_s + sdata[tid] - v;
    if (i < NN) d_off[b*(NN+1) + i] = excl;
    __syncthreads();
    if (tid == 1023) carry_s += sdata[1023];
    __syncthreads();
  }
  if (tid == 0) d_off[b*(NN+1) + NN] = carry_s;
}

// ---- scatter: build packed edge records {dst, w0, w1, w2} ----
__global__ __launch_bounds__(256) void k_csr_scatter(const int* __restrict__ edges,
                                                     const float* __restrict__ egw) {
  int e = blockIdx.x*256 + threadIdx.x;
  if (e >= BB*EE) return;
  int b = e / EE;
  int src = edges[e*2 + 0];
  int dst = edges[e*2 + 1];
  int pos = atomicAdd(&d_cursor[b*NN + src], 1);
  d_erec[(size_t)b*EE + d_off[b*(NN+1) + src] + pos] =
      make_float4(__int_as_float(dst), egw[e*3+0], egw[e*3+1], egw[e*3+2]);
}

// ---- fc0 -> hnewT + stackT h slab ----
__global__ __launch_bounds__(256) void k_h0(const float* __restrict__ x,
                                            const float* __restrict__ t,
                                            const float* __restrict__ w,
                                            const float* __restrict__ bias) {
  int tid = blockIdx.x*256 + threadIdx.x;   // (b*NN+n)*CC + c
  int c = tid & 127;
  int bn = tid >> 7;
  int b = bn / NN, n = bn % NN;
  const float* xv = x + bn*3;
  float acc = bias[c] + xv[0]*w[c] + xv[1]*w[CC+c] + xv[2]*w[2*CC+c]
            + t[bn]*w[3*CC+c];
  size_t row = (size_t)(b*NP + n);
  d_hnewT[row*CC + c] = acc;
  d_stackT[row*KR + 256 + c] = f2bf(acc);
}

// ---- layer-0 hTwT: hnewT [n][c] * nw -> bf16 [c][n], zero-pads ----
__global__ __launch_bounds__(256) void k_hT0() {
  __shared__ unsigned short t[128][136];
  int chunk = blockIdx.x;   // NCHK
  int b = blockIdx.y;
  int n0 = chunk*128;
  int tid = threadIdx.x;
  int cl = tid & 127, ng = tid >> 7;
  for (int nn = ng; nn < 128; nn += 2) {
    int n = n0 + nn;
    unsigned short v = 0;
    if (n < NN) v = f2bf(d_hnewT[((size_t)(b*NP + n))*CC + cl] * d_nw[b*NN + n]);
    t[nn][cl] = v;
  }
  __syncthreads();
  int nl = tid & 31, cg = tid >> 5;
  for (int c = cg; c < 128; c += 8)
    for (int nn2 = 0; nn2 < 128; nn2 += 32)
      d_hTwT[((size_t)(b*CC + c))*NP + n0 + nn2 + nl] = t[nn2 + nl][c];
}

// ---- gemm1 MFMA: part[c][k] += sum_n hTwT[c][n]*bcT/bsT[k][n] ----
__global__ __launch_bounds__(256) void k_gemm1m() {
  __shared__ unsigned short Bsh[2][128][40];
  int chunk = blockIdx.x;   // G1CH
  int b = blockIdx.y;
  int tid = threadIdx.x, lane = tid & 63, wid = tid >> 6;
  int q = lane >> 4, m = lane & 15;
  f32x4 accC[2][8], accS[2][8];
  #pragma unroll
  for (int i = 0; i < 2; i++)
    #pragma unroll
    for (int j = 0; j < 8; j++) { accC[i][j] = (f32x4){0.f,0.f,0.f,0.f}; accS[i][j] = (f32x4){0.f,0.f,0.f,0.f}; }
  const unsigned short* Ab = d_hTwT + (size_t)b*CC*NP;
  const unsigned short* Bcp = d_bcT + (size_t)b*KK*NP;
  const unsigned short* Bsp = d_bsT + (size_t)b*KK*NP;
  int n0 = chunk*G1N;
  for (int s = 0; s < G1N/32; s++) {
    int nb = n0 + s*32;
    if (nb >= NP) break;
    __syncthreads();
    {
      int arr = tid >> 7, row = tid & 127;
      const unsigned short* src = (arr ? Bsp : Bcp) + (size_t)row*NP + nb;
      unsigned short* dr = &Bsh[arr][row][0];
      *(uint4*)&dr[0]  = *(const uint4*)&src[0];
      *(uint4*)&dr[8]  = *(const uint4*)&src[8];
      *(uint4*)&dr[16] = *(const uint4*)&src[16];
      *(uint4*)&dr[24] = *(const uint4*)&src[24];
    }
    __syncthreads();
    bf16x8 a0 = *(const bf16x8*)(Ab + (size_t)(wid*32 + m)*NP + nb + q*8);
    bf16x8 a1 = *(const bf16x8*)(Ab + (size_t)(wid*32 + 16 + m)*NP + nb + q*8);
    #pragma unroll
    for (int kt = 0; kt < 8; kt++) {
      bf16x8 bcf = *(const bf16x8*)&Bsh[0][kt*16 + m][q*8];
      bf16x8 bsf = *(const bf16x8*)&Bsh[1][kt*16 + m][q*8];
      accC[0][kt] = __builtin_amdgcn_mfma_f32_16x16x32_bf16(a0, bcf, accC[0][kt], 0, 0, 0);
      accC[1][kt] = __builtin_amdgcn_mfma_f32_16x16x32_bf16(a1, bcf, accC[1][kt], 0, 0, 0);
      accS[0][kt] = __builtin_amdgcn_mfma_f32_16x16x32_bf16(a0, bsf, accS[0][kt], 0, 0, 0);
      accS[1][kt] = __builtin_amdgcn_mfma_f32_16x16x32_bf16(a1, bsf, accS[1][kt], 0, 0, 0);
    }
  }
  float* base = d_part + (((size_t)b*G1CH + chunk)*2)*16384;
  #pragma unroll
  for (int mt = 0; mt < 2; mt++)
    #pragma unroll
    for (int kt = 0; kt < 8; kt++)
      #pragma unroll
      for (int r = 0; r < 4; r++) {
        int c = wid*32 + mt*16 + q*4 + r;
        int k = kt*16 + m;
        base[c*128 + k]         =  accC[mt][kt][r];
        base[16384 + c*128 + k] = -accS[mt][kt][r];   // xs = -sum
      }
}

// ---- reduce split-k partials -> xc, xs ----
__global__ __launch_bounds__(256) void k_reduce1() {
  int tid = blockIdx.x*256 + threadIdx.x;   // BB*2*128*128 = 65536
  int k = tid & 127;
  int c = (tid >> 7) & 127;
  int arr = (tid >> 14) & 1;
  int b = tid >> 15;
  const float* p = d_part + (((size_t)b*G1CH)*2 + arr)*16384 + c*128 + k;
  float acc = 0.f;
  for (int ch = 0; ch < G1CH; ch++) acc += p[(size_t)ch*2*16384];
  if (arr == 0) d_xc[(b*CC + c)*KK + k] = acc;
  else          d_xs[(b*CC + c)*KK + k] = acc;
}

// ---- x0 partials from hTwT bf16 ----
__global__ __launch_bounds__(256) void k_x0() {
  int chunk = blockIdx.x;   // NCHK
  int b = blockIdx.y;
  int tid = threadIdx.x;
  int c = tid >> 1, half = tid & 1;
  const unsigned short* p = d_hTwT + ((size_t)(b*CC + c))*NP + chunk*128 + half*64;
  float acc = 0.f;
  #pragma unroll
  for (int i = 0; i < 8; i++) {
    ushort4 v0 = *(const ushort4*)&p[i*8];
    ushort4 v1 = *(const ushort4*)&p[i*8 + 4];
    acc += bf2f(v0.x) + bf2f(v0.y) + bf2f(v0.z) + bf2f(v0.w)
         + bf2f(v1.x) + bf2f(v1.y) + bf2f(v1.z) + bf2f(v1.w);
  }
  __shared__ float red[128][2];
  red[c][half] = acc;
  __syncthreads();
  if (half == 0) d_x0p[(b*NCHK + chunk)*CC + c] = red[c][0] + red[c][1];
}

// ---- spectral mix per k ----
__global__ __launch_bounds__(128) void k_spec(const float* __restrict__ Wc,
                                              const float* __restrict__ Ws, int l) {
  int b = blockIdx.x >> 7;
  int o = blockIdx.x & 127;
  int k = threadIdx.x;
  const float* wcp = Wc + ((size_t)(l*CC)*CC + o)*KK + k;
  const float* wsp = Ws + ((size_t)(l*CC)*CC + o)*KK + k;
  float fc = 0.f, fs = 0.f;
  for (int i = 0; i < CC; i++) {
    float xcv = d_xc[(b*CC + i)*KK + k];
    float xsv = d_xs[(b*CC + i)*KK + k];
    float wcv = wcp[(size_t)i*CC*KK];
    float wsv = wsp[(size_t)i*CC*KK];
    fc += xcv*wcv - xsv*wsv;
    fs += xsv*wcv + xcv*wsv;
  }
  d_fcv[(b*CC + o)*KK + k] = fc;
  d_fsv[(b*CC + o)*KK + k] = fs;
}

// ---- f0 + full bias ----
__global__ __launch_bounds__(128) void k_f0(const float* __restrict__ W0,
                                            const float* __restrict__ wsb,
                                            const float* __restrict__ gwsb, int l) {
  int b = blockIdx.x;
  int o = threadIdx.x;
  __shared__ float sx[CC];
  float xv = 0.f;
  for (int p = 0; p < NCHK; p++) xv += d_x0p[(b*NCHK + p)*CC + o];
  sx[o] = xv;
  __syncthreads();
  float acc = 0.f;
  for (int i = 0; i < CC; i++) acc += sx[i]*W0[(l*CC + i)*CC + o];
  d_bias[b*CC + o] = acc + wsb[l*CC + o] + gwsb[l*CC + o];
}

// ---- build A matrix [b][o][r] bf16 ----
__global__ __launch_bounds__(128) void k_buildAb(const float* __restrict__ wsw,
                                                 const float* __restrict__ gwsw, int l) {
  int bo = blockIdx.x;
  int b = bo >> 7, o = bo & 127;
  int t = threadIdx.x;
  unsigned short* dst = d_Amatb + (size_t)bo*KR;
  dst[t]       = f2bf( 2.f*d_fcv[(size_t)bo*KK + t]);
  dst[128 + t] = f2bf(-2.f*d_fsv[(size_t)bo*KK + t]);
  dst[256 + t] = f2bf(wsw[(l*CC + o)*CC + t]);
  #pragma unroll
  for (int j = 0; j < 3; j++)
    dst[384 + j*128 + t] = f2bf(gwsw[(size_t)(l*CC + o)*GJ + j*128 + t]);
}

// ---- fc1w transpose to [o2][c] bf16 ----
__global__ __launch_bounds__(128) void k_fc1w(const float* __restrict__ fc1w) {
  int c = blockIdx.x;
  int o2 = threadIdx.x;
  d_fc1wb[o2*CC + c] = f2bf(fc1w[c*FCC + o2]);
}

// ---- CSR edge gradient via packed records -> stackT g slab ----
__global__ __launch_bounds__(128) void k_grad_csr() {
  int bn = blockIdx.x;            // b*NN + n
  int b = bn / NN, n = bn % NN;
  int c = threadIdx.x;
  int beg = d_off[b*(NN+1) + n];
  int end = d_off[b*(NN+1) + n + 1];
  const float4* rp = d_erec + (size_t)b*EE;
  const float* hb = d_hnewT + (size_t)b*NP*CC + c;
  float a0 = 0.f, a1 = 0.f, a2 = 0.f;
  float sw0 = 0.f, sw1 = 0.f, sw2 = 0.f;
  int p = beg;
  for (; p + 2 <= end; p += 2) {
    float4 r1 = rp[p], r2 = rp[p+1];
    float f1 = hb[(size_t)__float_as_int(r1.x)*CC];
    float f2 = hb[(size_t)__float_as_int(r2.x)*CC];
    a0 += r1.y*f1 + r2.y*f2;
    a1 += r1.z*f1 + r2.z*f2;
    a2 += r1.w*f1 + r2.w*f2;
    sw0 += r1.y + r2.y; sw1 += r1.z + r2.z; sw2 += r1.w + r2.w;
  }
  if (p < end) {
    float4 r1 = rp[p];
    float f1 = hb[(size_t)__float_as_int(r1.x)*CC];
    a0 += r1.y*f1; a1 += r1.z*f1; a2 += r1.w*f1;
    sw0 += r1.y; sw1 += r1.z; sw2 += r1.w;
  }
  float fs = d_hnewT[((size_t)(b*NP + n))*CC + c];
  a0 -= sw0*fs; a1 -= sw1*fs; a2 -= sw2*fs;
  unsigned short* gp = d_stackT + ((size_t)(b*NP + n))*KR + 384;
  gp[c]        = f2bf(a0/(1.f + fabsf(a0)));
  gp[CC + c]   = f2bf(a1/(1.f + fabsf(a1)));
  gp[2*CC + c] = f2bf(a2/(1.f + fabsf(a2)));
}

// ---- MFMA GEMM v4: 32n x 128o tile, 4 waves (2n x 2o), LDS dbuf, 1 barrier/chunk ----
// Out[b][n][o] = sum_k stackT[b][n][koff+k] * W[b?][o][k] + bias[o]
__global__ __launch_bounds__(256) void k_mfma(int koff, int K,
                                              const unsigned short* __restrict__ W, size_t wstride,
                                              float* __restrict__ Out,
                                              const float* __restrict__ bias, int bias_stride,
                                              int gelu, int aux) {
  __shared__ unsigned short As[2][32*40];    // [buf][n-row][k] pad 40
  __shared__ unsigned short Bs[2][128*40];   // [buf][o-row][k]
  int b = blockIdx.z;
  int n_base = blockIdx.x*32;
  int tid = threadIdx.x;
  int lane = tid & 63, wid = tid >> 6;
  int wr = wid >> 1, wc = wid & 1;           // n-group, o-group
  int q = lane >> 4, m = lane & 15;

  f32x4 acc[4];
  #pragma unroll
  for (int j = 0; j < 4; j++) acc[j] = (f32x4){0.f,0.f,0.f,0.f};

  const unsigned short* Wb = W + (size_t)b*wstride;
  const unsigned short* Ab = d_stackT + (size_t)b*NP*KR + koff;

#define STAGE(k0, d) { \
    if (tid < 128) { \
      int rowA = tid >> 2; int e8A = (tid & 3)*8; \
      *(uint4*)&As[d][rowA*40 + e8A] = *(const uint4*)(Ab + (size_t)(n_base + rowA)*KR + (k0) + e8A); \
    } \
    _Pragma("unroll") \
    for (int i_ = 0; i_ < 2; i_++) { \
      int idx_ = tid + i_*256; int rowB = idx_ >> 2; int e8B = (idx_ & 3)*8; \
      *(uint4*)&Bs[d][rowB*40 + e8B] = *(const uint4*)(Wb + (size_t)rowB*K + (k0) + e8B); \
    } }

  STAGE(0, 0)
  int cur = 0;
  for (int k0 = 0; k0 < K; k0 += 32) {
    __syncthreads();
    if (k0 + 32 < K) STAGE(k0 + 32, cur ^ 1)
    bf16x8 a = *(const bf16x8*)&As[cur][(wr*16 + m)*40 + q*8];
    #pragma unroll
    for (int ot = 0; ot < 4; ot++) {
      bf16x8 bf = *(const bf16x8*)&Bs[cur][(wc*64 + ot*16 + m)*40 + q*8];
      acc[ot] = __builtin_amdgcn_mfma_f32_16x16x32_bf16(a, bf, acc[ot], 0, 0, 0);
    }
    cur ^= 1;
  }
#undef STAGE

  const float* bp = bias + (size_t)b*bias_stride;
  int nb4 = n_base + wr*16 + q*4;
  float nw4[4];
  #pragma unroll
  for (int r = 0; r < 4; r++)
    nw4[r] = (aux && nb4 + r < NN) ? d_nw[b*NN + nb4 + r] : 0.f;
  #pragma unroll
  for (int ot = 0; ot < 4; ot++) {
    int o = wc*64 + ot*16 + m;
    float bvv = bp[o];
    float vals[4];
    #pragma unroll
    for (int r = 0; r < 4; r++) {
      float v = acc[ot][r] + bvv;
      if (gelu) v = 0.5f*v*(1.f + erff(v*0.70710678118f));
      vals[r] = v;
      Out[((size_t)(b*NP + nb4 + r))*128 + o] = v;
      if (aux && nb4 + r < NN)
        d_stackT[((size_t)(b*NP + nb4 + r))*KR + 256 + o] = f2bf(v);
    }
    if (aux) {
      ushort4 pk;
      pk.x = f2bf(vals[0]*nw4[0]);
      pk.y = f2bf(vals[1]*nw4[1]);
      pk.z = f2bf(vals[2]*nw4[2]);
      pk.w = f2bf(vals[3]*nw4[3]);
      *(ushort4*)&d_hTwT[((size_t)(b*CC + o))*NP + nb4] = pk;
    }
  }
}

// ---- fc2 + residual; u = d_uT [b][n][o2] ----
__global__ __launch_bounds__(256) void k_out(const float* __restrict__ x,
                                             const float* __restrict__ t,
                                             const float* __restrict__ fc2w,
                                             const float* __restrict__ fc2b,
                                             float* __restrict__ out) {
  int tid = blockIdx.x*256 + threadIdx.x;
  if (tid >= BB*NN) return;
  int b = tid / NN, n = tid % NN;
  const float* up = d_uT + ((size_t)(b*NP + n))*FCC;
  float a0 = fc2b[0], a1 = fc2b[1], a2v = fc2b[2];
  #pragma unroll 4
  for (int o2 = 0; o2 < FCC; o2 += 4) {
    float4 uv = *(const float4*)&up[o2];
    a0  += uv.x*fc2w[(o2+0)*3+0] + uv.y*fc2w[(o2+1)*3+0] + uv.z*fc2w[(o2+2)*3+0] + uv.w*fc2w[(o2+3)*3+0];
    a1  += uv.x*fc2w[(o2+0)*3+1] + uv.y*fc2w[(o2+1)*3+1] + uv.z*fc2w[(o2+2)*3+1] + uv.w*fc2w[(o2+3)*3+1];
    a2v += uv.x*fc2w[(o2+0)*3+2] + uv.y*fc2w[(o2+1)*3+2] + uv.z*fc2w[(o2+2)*3+2] + uv.w*fc2w[(o2+3)*3+2];
  }
  float tv = t[tid];
  out[tid*3 + 0] = x[tid*3 + 0] + tv*a0;
  out[tid*3 + 1] = x[tid*3 + 1] + tv*a1;
  out[tid*3 + 2] = x[tid*3 + 2] + tv*a2v;
}

extern "C" void kernel_launch(void* const* d_in, const int* in_sizes, int n_in,
                              void* d_out, int out_size, void* d_ws, size_t ws_size,
                              hipStream_t stream) {
  const float* x     = (const float*)d_in[0];
  const float* t     = (const float*)d_in[1];
  const float* nodes = (const float*)d_in[3];
  const float* nodew = (const float*)d_in[4];
  const int*   edges = (const int*)d_in[5];
  const float* egw   = (const float*)d_in[6];
  const float* modes = (const float*)d_in[7];
  const float* spL   = (const float*)d_in[8];
  const float* fc0w  = (const float*)d_in[9];
  const float* fc0b  = (const float*)d_in[10];
  const float* Wc    = (const float*)d_in[11];
  const float* Ws    = (const float*)d_in[12];
  const float* W0    = (const float*)d_in[13];
  const float* wsw   = (const float*)d_in[14];
  const float* wsb   = (const float*)d_in[15];
  const float* gwsw  = (const float*)d_in[16];
  const float* gwsb  = (const float*)d_in[17];
  const float* fc1w  = (const float*)d_in[18];
  const float* fc1b  = (const float*)d_in[19];
  const float* fc2w  = (const float*)d_in[20];
  const float* fc2b  = (const float*)d_in[21];
  float* out = (float*)d_out;

  unsigned short* d_Amatb_p; hipGetSymbolAddress((void**)&d_Amatb_p, HIP_SYMBOL(d_Amatb));
  unsigned short* d_fc1wb_p; hipGetSymbolAddress((void**)&d_fc1wb_p, HIP_SYMBOL(d_fc1wb));
  float* d_hnewT_p; hipGetSymbolAddress((void**)&d_hnewT_p, HIP_SYMBOL(d_hnewT));
  float* d_uT_p;    hipGetSymbolAddress((void**)&d_uT_p,    HIP_SYMBOL(d_uT));
  float* d_bias_p;  hipGetSymbolAddress((void**)&d_bias_p,  HIP_SYMBOL(d_bias));

  hipLaunchKernelGGL(k_basis, dim3(BB*NN), dim3(128), 0, stream, nodes, nodew, modes, spL);
  hipLaunchKernelGGL(k_basisT, dim3(628*BB), dim3(256), 0, stream);
  hipLaunchKernelGGL(k_h0, dim3(BB*NN*CC/256), dim3(256), 0, stream, x, t, fc0w, fc0b);
  hipLaunchKernelGGL(k_hT0, dim3(NCHK, BB), dim3(256), 0, stream);
  hipLaunchKernelGGL(k_fc1w, dim3(CC), dim3(FCC), 0, stream, fc1w);
  // CSR build (once; edges constant across layers)
  hipLaunchKernelGGL(k_csr_zero, dim3((BB*NN + 255)/256), dim3(256), 0, stream);
  hipLaunchKernelGGL(k_csr_count, dim3((BB*EE + 255)/256), dim3(256), 0, stream, edges);
  hipLaunchKernelGGL(k_csr_scan, dim3(BB), dim3(1024), 0, stream);
  hipLaunchKernelGGL(k_csr_scatter, dim3((BB*EE + 255)/256), dim3(256), 0, stream, edges, egw);

  for (int l = 0; l < LL; l++) {
    hipLaunchKernelGGL(k_gemm1m, dim3(G1CH, BB), dim3(256), 0, stream);
    hipLaunchKernelGGL(k_reduce1, dim3(256), dim3(256), 0, stream);
    hipLaunchKernelGGL(k_x0, dim3(NCHK, BB), dim3(256), 0, stream);
    hipLaunchKernelGGL(k_spec, dim3(BB*CC), dim3(128), 0, stream, Wc, Ws, l);
    hipLaunchKernelGGL(k_f0, dim3(BB), dim3(CC), 0, stream, W0, wsb, gwsb, l);
    hipLaunchKernelGGL(k_buildAb, dim3(BB*CC), dim3(128), 0, stream, wsw, gwsw, l);
    hipLaunchKernelGGL(k_grad_csr, dim3(BB*NN), dim3(128), 0, stream);
    hipLaunchKernelGGL(k_mfma, dim3(NP/32, 1, BB), dim3(256), 0, stream,
                       0, KR, d_Amatb_p, (size_t)CC*KR, d_hnewT_p, d_bias_p, CC,
                       (l != LL-1) ? 1 : 0, 1);
  }

  // fc1 via MFMA on the h slab
  hipLaunchKernelGGL(k_mfma, dim3(NP/32, 1, BB), dim3(256), 0, stream,
                     256, CC, d_fc1wb_p, (size_t)0, d_uT_p, fc1b, 0, 1, 0);
  hipLaunchKernelGGL(k_out, dim3((BB*NN + 255)/256), dim3(256), 0, stream, x, t, fc2w, fc2b, out);
}

// Round 11
// 564.002 us; speedup vs baseline: 1.2602x; 1.0430x over previous
//
#include <hip/hip_runtime.h>
#include <math.h>

#define BB 2
#define NN 20000
#define EE 100000
#define DD 3
#define KK 128
#define CC 128
#define LL 3
#define FCC 128
#define GJ (DD*CC)    // 384
#define KR 768        // stacked contraction: 128 bc + 128 bs + 128 h + 384 g
#define NP 20096      // padded N: 157 tiles * 128
#define NCHK 157      // 128-row chunks
#define G1CH 157      // gemm1 split-k chunks (128 n each)
#define G1N 128

typedef __attribute__((ext_vector_type(8))) short bf16x8;
typedef __attribute__((ext_vector_type(4))) float f32x4;

__device__ inline unsigned short f2bf(float f) {
  unsigned int u = __float_as_uint(f);
  u += 0x7fffu + ((u >> 16) & 1u);
  return (unsigned short)(u >> 16);
}
__device__ inline float bf2f(unsigned short u) {
  return __uint_as_float(((unsigned int)u) << 16);
}

// ---- scratch (device globals) ----
__device__ float d_nw[BB*NN];
__device__ __align__(16) unsigned short d_stackT[(size_t)BB*NP*KR]; // [b][n][r] bf16: 0 bc,128 bs,256 h,384 g
__device__ __align__(16) unsigned short d_bcT[(size_t)BB*KK*NP];    // [b][k][n] bf16, pad-zeroed
__device__ __align__(16) unsigned short d_bsT[(size_t)BB*KK*NP];
__device__ __align__(16) unsigned short d_hTwT[(size_t)BB*CC*NP];   // [b][c][n] bf16 = h*nw, pad-zeroed
__device__ __align__(16) float d_uT[(size_t)BB*NP*FCC];     // fc1 out [b][n][o2] fp32
__device__ __align__(16) unsigned short d_Amatb[BB*CC*KR];  // [b][o][r] bf16
__device__ __align__(16) unsigned short d_fc1wb[FCC*CC];    // [o2][c] bf16
__device__ __align__(16) float d_part[(size_t)BB*G1CH*2*128*128];   // [b][chunk][arr][c*128+k]
__device__ float d_xc[BB*CC*KK];
__device__ float d_xs[BB*CC*KK];
__device__ float d_x0p[BB*NCHK*CC];
__device__ float d_fcp[BB*CC*8*KK];   // spec partials [b][o][ch][k]
__device__ float d_fsp[BB*CC*8*KK];
__device__ float d_bias[BB*CC];
// CSR
__device__ int d_cnt[BB*NN];
__device__ int d_cursor[BB*NN];
__device__ int d_off[BB*(NN+1)];
__device__ __align__(16) float4 d_erec[(size_t)BB*EE];      // {dst_bits, w0, w1, w2}

// ---- basis -> stackT bc/bs slabs (bf16) ----
__global__ __launch_bounds__(128) void k_basis(const float* __restrict__ nodes,
                                               const float* __restrict__ nodew,
                                               const float* __restrict__ modes,
                                               const float* __restrict__ spL) {
  int bn = blockIdx.x;            // b*NN + n
  int k  = threadIdx.x;
  int b = bn / NN, n = bn % NN;
  float x0 = nodes[bn*3+0], x1 = nodes[bn*3+1], x2 = nodes[bn*3+2];
  float tmp = x0*modes[k*3+0]*spL[0] + x1*modes[k*3+1]*spL[1] + x2*modes[k*3+2]*spL[2];
  float cv = cosf(tmp), sv = sinf(tmp);
  size_t row = (size_t)(b*NP + n);
  d_stackT[row*KR + k]       = f2bf(cv);
  d_stackT[row*KR + 128 + k] = f2bf(sv);
  if (k == 0) d_nw[bn] = nodew[bn];
}

// ---- transpose stackT bc/bs slabs -> bcT/bsT [k][n] bf16 (once; zero-pads n>=NN) ----
__global__ __launch_bounds__(256) void k_basisT() {
  __shared__ unsigned short t1[32][136];
  __shared__ unsigned short t2[32][136];
  int blk = blockIdx.x;          // 628 * BB
  int nt = blk % 628, b = blk / 628;
  int n0 = nt*32;
  int tid = threadIdx.x;
  int kl = tid & 127, ng = tid >> 7;
  for (int nn = ng; nn < 32; nn += 2) {
    int n = n0 + nn;
    unsigned short cv = 0, sv = 0;
    if (n < NN) {
      const unsigned short* sp = d_stackT + ((size_t)(b*NP + n))*KR;
      cv = sp[kl]; sv = sp[128 + kl];
    }
    t1[nn][kl] = cv;
    t2[nn][kl] = sv;
  }
  __syncthreads();
  int nl = tid & 31, kg = tid >> 5;
  for (int k = kg; k < 128; k += 8) {
    d_bcT[((size_t)(b*KK + k))*NP + n0 + nl] = t1[nl][k];
    d_bsT[((size_t)(b*KK + k))*NP + n0 + nl] = t2[nl][k];
  }
}

// ---- CSR build ----
__global__ __launch_bounds__(256) void k_csr_zero() {
  int tid = blockIdx.x*256 + threadIdx.x;
  if (tid < BB*NN) { d_cnt[tid] = 0; d_cursor[tid] = 0; }
}

__global__ __launch_bounds__(256) void k_csr_count(const int* __restrict__ edges) {
  int e = blockIdx.x*256 + threadIdx.x;
  if (e >= BB*EE) return;
  int b = e / EE;
  int src = edges[e*2 + 0];
  atomicAdd(&d_cnt[b*NN + src], 1);
}

__global__ __launch_bounds__(1024) void k_csr_scan() {
  int b = blockIdx.x;
  __shared__ int sdata[1024];
  __shared__ int carry_s;
  int tid = threadIdx.x;
  if (tid == 0) carry_s = 0;
  __syncthreads();
  for (int chunk = 0; chunk < 20; ++chunk) {
    int i = chunk*1024 + tid;
    int v = (i < NN) ? d_cnt[b*NN + i] : 0;
    sdata[tid] = v;
    __syncthreads();
    for (int s = 1; s < 1024; s <<= 1) {
      int tv = (tid >= s) ? sdata[tid - s] : 0;
      __syncthreads();
      sdata[tid] += tv;
      __syncthreads();
    }
    int excl = carry_s + sdata[tid] - v;
    if (i < NN) d_off[b*(NN+1) + i] = excl;
    __syncthreads();
    if (tid == 1023) carry_s += sdata[1023];
    __syncthreads();
  }
  if (tid == 0) d_off[b*(NN+1) + NN] = carry_s;
}

// ---- scatter: build packed edge records {dst, w0, w1, w2} ----
__global__ __launch_bounds__(256) void k_csr_scatter(const int* __restrict__ edges,
                                                     const float* __restrict__ egw) {
  int e = blockIdx.x*256 + threadIdx.x;
  if (e >= BB*EE) return;
  int b = e / EE;
  int src = edges[e*2 + 0];
  int dst = edges[e*2 + 1];
  int pos = atomicAdd(&d_cursor[b*NN + src], 1);
  d_erec[(size_t)b*EE + d_off[b*(NN+1) + src] + pos] =
      make_float4(__int_as_float(dst), egw[e*3+0], egw[e*3+1], egw[e*3+2]);
}

// ---- fc0 -> stackT h slab (bf16) ----
__global__ __launch_bounds__(256) void k_h0(const float* __restrict__ x,
                                            const float* __restrict__ t,
                                            const float* __restrict__ w,
                                            const float* __restrict__ bias) {
  int tid = blockIdx.x*256 + threadIdx.x;   // (b*NN+n)*CC + c
  int c = tid & 127;
  int bn = tid >> 7;
  int b = bn / NN, n = bn % NN;
  const float* xv = x + bn*3;
  float acc = bias[c] + xv[0]*w[c] + xv[1]*w[CC+c] + xv[2]*w[2*CC+c]
            + t[bn]*w[3*CC+c];
  d_stackT[((size_t)(b*NP + n))*KR + 256 + c] = f2bf(acc);
}

// ---- layer-0 hTwT: stackT h slab (bf16) * nw -> bf16 [c][n], zero-pads ----
__global__ __launch_bounds__(256) void k_hT0() {
  __shared__ unsigned short t[128][136];
  int chunk = blockIdx.x;   // NCHK
  int b = blockIdx.y;
  int n0 = chunk*128;
  int tid = threadIdx.x;
  int cl = tid & 127, ng = tid >> 7;
  for (int nn = ng; nn < 128; nn += 2) {
    int n = n0 + nn;
    unsigned short v = 0;
    if (n < NN) {
      float hv = bf2f(d_stackT[((size_t)(b*NP + n))*KR + 256 + cl]);
      v = f2bf(hv * d_nw[b*NN + n]);
    }
    t[nn][cl] = v;
  }
  __syncthreads();
  int nl = tid & 31, cg = tid >> 5;
  for (int c = cg; c < 128; c += 8)
    for (int nn2 = 0; nn2 < 128; nn2 += 32)
      d_hTwT[((size_t)(b*CC + c))*NP + n0 + nn2 + nl] = t[nn2 + nl][c];
}

// ---- gemm1 MFMA: part[c][k] += sum_n hTwT[c][n]*bcT/bsT[k][n] ----
__global__ __launch_bounds__(256) void k_gemm1m() {
  __shared__ unsigned short Bsh[2][128][40];
  int chunk = blockIdx.x;   // G1CH
  int b = blockIdx.y;
  int tid = threadIdx.x, lane = tid & 63, wid = tid >> 6;
  int q = lane >> 4, m = lane & 15;
  f32x4 accC[2][8], accS[2][8];
  #pragma unroll
  for (int i = 0; i < 2; i++)
    #pragma unroll
    for (int j = 0; j < 8; j++) { accC[i][j] = (f32x4){0.f,0.f,0.f,0.f}; accS[i][j] = (f32x4){0.f,0.f,0.f,0.f}; }
  const unsigned short* Ab = d_hTwT + (size_t)b*CC*NP;
  const unsigned short* Bcp = d_bcT + (size_t)b*KK*NP;
  const unsigned short* Bsp = d_bsT + (size_t)b*KK*NP;
  int n0 = chunk*G1N;
  for (int s = 0; s < G1N/32; s++) {
    int nb = n0 + s*32;
    __syncthreads();
    {
      int arr = tid >> 7, row = tid & 127;
      const unsigned short* src = (arr ? Bsp : Bcp) + (size_t)row*NP + nb;
      unsigned short* dr = &Bsh[arr][row][0];
      *(uint4*)&dr[0]  = *(const uint4*)&src[0];
      *(uint4*)&dr[8]  = *(const uint4*)&src[8];
      *(uint4*)&dr[16] = *(const uint4*)&src[16];
      *(uint4*)&dr[24] = *(const uint4*)&src[24];
    }
    __syncthreads();
    bf16x8 a0 = *(const bf16x8*)(Ab + (size_t)(wid*32 + m)*NP + nb + q*8);
    bf16x8 a1 = *(const bf16x8*)(Ab + (size_t)(wid*32 + 16 + m)*NP + nb + q*8);
    #pragma unroll
    for (int kt = 0; kt < 8; kt++) {
      bf16x8 bcf = *(const bf16x8*)&Bsh[0][kt*16 + m][q*8];
      bf16x8 bsf = *(const bf16x8*)&Bsh[1][kt*16 + m][q*8];
      accC[0][kt] = __builtin_amdgcn_mfma_f32_16x16x32_bf16(a0, bcf, accC[0][kt], 0, 0, 0);
      accC[1][kt] = __builtin_amdgcn_mfma_f32_16x16x32_bf16(a1, bcf, accC[1][kt], 0, 0, 0);
      accS[0][kt] = __builtin_amdgcn_mfma_f32_16x16x32_bf16(a0, bsf, accS[0][kt], 0, 0, 0);
      accS[1][kt] = __builtin_amdgcn_mfma_f32_16x16x32_bf16(a1, bsf, accS[1][kt], 0, 0, 0);
    }
  }
  float* base = d_part + (((size_t)b*G1CH + chunk)*2)*16384;
  #pragma unroll
  for (int mt = 0; mt < 2; mt++)
    #pragma unroll
    for (int kt = 0; kt < 8; kt++)
      #pragma unroll
      for (int r = 0; r < 4; r++) {
        int c = wid*32 + mt*16 + q*4 + r;
        int k = kt*16 + m;
        base[c*128 + k]         =  accC[mt][kt][r];
        base[16384 + c*128 + k] = -accS[mt][kt][r];   // xs = -sum
      }
}

// ---- reduce split-k partials -> xc, xs ----
__global__ __launch_bounds__(256) void k_reduce1() {
  int tid = blockIdx.x*256 + threadIdx.x;   // BB*2*128*128 = 65536
  int k = tid & 127;
  int c = (tid >> 7) & 127;
  int arr = (tid >> 14) & 1;
  int b = tid >> 15;
  const float* p = d_part + (((size_t)b*G1CH)*2 + arr)*16384 + c*128 + k;
  float acc = 0.f;
  for (int ch = 0; ch < G1CH; ch++) acc += p[(size_t)ch*2*16384];
  if (arr == 0) d_xc[(b*CC + c)*KK + k] = acc;
  else          d_xs[(b*CC + c)*KK + k] = acc;
}

// ---- x0 partials from hTwT bf16 ----
__global__ __launch_bounds__(256) void k_x0() {
  int chunk = blockIdx.x;   // NCHK
  int b = blockIdx.y;
  int tid = threadIdx.x;
  int c = tid >> 1, half = tid & 1;
  const unsigned short* p = d_hTwT + ((size_t)(b*CC + c))*NP + chunk*128 + half*64;
  float acc = 0.f;
  #pragma unroll
  for (int i = 0; i < 8; i++) {
    ushort4 v0 = *(const ushort4*)&p[i*8];
    ushort4 v1 = *(const ushort4*)&p[i*8 + 4];
    acc += bf2f(v0.x) + bf2f(v0.y) + bf2f(v0.z) + bf2f(v0.w)
         + bf2f(v1.x) + bf2f(v1.y) + bf2f(v1.z) + bf2f(v1.w);
  }
  __shared__ float red[128][2];
  red[c][half] = acc;
  __syncthreads();
  if (half == 0) d_x0p[(b*NCHK + chunk)*CC + c] = red[c][0] + red[c][1];
}

// ---- spectral mix, i-chunked (8 chunks of 16) -> partials ----
__global__ __launch_bounds__(128) void k_spec(const float* __restrict__ Wc,
                                              const float* __restrict__ Ws, int l) {
  int bo = blockIdx.x;          // b*CC + o
  int ch = blockIdx.y;          // 0..7
  int b = bo >> 7;
  int o = bo & 127;
  int k = threadIdx.x;
  int i0 = ch*16;
  const float* wcp = Wc + ((size_t)(l*CC + i0)*CC + o)*KK + k;
  const float* wsp = Ws + ((size_t)(l*CC + i0)*CC + o)*KK + k;
  float fc = 0.f, fs = 0.f;
  #pragma unroll 4
  for (int j = 0; j < 16; j++) {
    int i = i0 + j;
    float xcv = d_xc[(b*CC + i)*KK + k];
    float xsv = d_xs[(b*CC + i)*KK + k];
    float wcv = wcp[(size_t)j*CC*KK];
    float wsv = wsp[(size_t)j*CC*KK];
    fc += xcv*wcv - xsv*wsv;
    fs += xsv*wcv + xcv*wsv;
  }
  d_fcp[((size_t)bo*8 + ch)*KK + k] = fc;
  d_fsp[((size_t)bo*8 + ch)*KK + k] = fs;
}

// ---- f0 + full bias ----
__global__ __launch_bounds__(128) void k_f0(const float* __restrict__ W0,
                                            const float* __restrict__ wsb,
                                            const float* __restrict__ gwsb, int l) {
  int b = blockIdx.x;
  int o = threadIdx.x;
  __shared__ float sx[CC];
  float xv = 0.f;
  for (int p = 0; p < NCHK; p++) xv += d_x0p[(b*NCHK + p)*CC + o];
  sx[o] = xv;
  __syncthreads();
  float acc = 0.f;
  for (int i = 0; i < CC; i++) acc += sx[i]*W0[(l*CC + i)*CC + o];
  d_bias[b*CC + o] = acc + wsb[l*CC + o] + gwsb[l*CC + o];
}

// ---- build A matrix [b][o][r] bf16 (sums spec partials) ----
__global__ __launch_bounds__(128) void k_buildAb(const float* __restrict__ wsw,
                                                 const float* __restrict__ gwsw, int l) {
  int bo = blockIdx.x;
  int b = bo >> 7, o = bo & 127;
  int t = threadIdx.x;
  float fc = 0.f, fs = 0.f;
  #pragma unroll
  for (int ch = 0; ch < 8; ch++) {
    fc += d_fcp[((size_t)bo*8 + ch)*KK + t];
    fs += d_fsp[((size_t)bo*8 + ch)*KK + t];
  }
  unsigned short* dst = d_Amatb + (size_t)bo*KR;
  dst[t]       = f2bf( 2.f*fc);
  dst[128 + t] = f2bf(-2.f*fs);
  dst[256 + t] = f2bf(wsw[(l*CC + o)*CC + t]);
  #pragma unroll
  for (int j = 0; j < 3; j++)
    dst[384 + j*128 + t] = f2bf(gwsw[(size_t)(l*CC + o)*GJ + j*128 + t]);
}

// ---- fc1w transpose to [o2][c] bf16 ----
__global__ __launch_bounds__(128) void k_fc1w(const float* __restrict__ fc1w) {
  int c = blockIdx.x;
  int o2 = threadIdx.x;
  d_fc1wb[o2*CC + c] = f2bf(fc1w[c*FCC + o2]);
}

// ---- CSR edge gradient (bf16 h gathers, 4-unrolled) -> stackT g slab ----
__global__ __launch_bounds__(128) void k_grad_csr() {
  int bn = blockIdx.x;            // b*NN + n
  int b = bn / NN, n = bn % NN;
  int c = threadIdx.x;
  int beg = d_off[b*(NN+1) + n];
  int end = d_off[b*(NN+1) + n + 1];
  const float4* rp = d_erec + (size_t)b*EE;
  const unsigned short* hb = d_stackT + (size_t)b*NP*KR + 256 + c;
  float a0 = 0.f, a1 = 0.f, a2 = 0.f;
  float sw0 = 0.f, sw1 = 0.f, sw2 = 0.f;
  int p = beg;
  for (; p + 4 <= end; p += 4) {
    float4 r1 = rp[p], r2 = rp[p+1], r3 = rp[p+2], r4 = rp[p+3];
    float f1 = bf2f(hb[(size_t)__float_as_int(r1.x)*KR]);
    float f2 = bf2f(hb[(size_t)__float_as_int(r2.x)*KR]);
    float f3 = bf2f(hb[(size_t)__float_as_int(r3.x)*KR]);
    float f4 = bf2f(hb[(size_t)__float_as_int(r4.x)*KR]);
    a0 += r1.y*f1 + r2.y*f2 + r3.y*f3 + r4.y*f4;
    a1 += r1.z*f1 + r2.z*f2 + r3.z*f3 + r4.z*f4;
    a2 += r1.w*f1 + r2.w*f2 + r3.w*f3 + r4.w*f4;
    sw0 += r1.y + r2.y + r3.y + r4.y;
    sw1 += r1.z + r2.z + r3.z + r4.z;
    sw2 += r1.w + r2.w + r3.w + r4.w;
  }
  for (; p < end; ++p) {
    float4 r1 = rp[p];
    float f1 = bf2f(hb[(size_t)__float_as_int(r1.x)*KR]);
    a0 += r1.y*f1; a1 += r1.z*f1; a2 += r1.w*f1;
    sw0 += r1.y; sw1 += r1.z; sw2 += r1.w;
  }
  float fs = bf2f(hb[(size_t)n*KR]);
  a0 -= sw0*fs; a1 -= sw1*fs; a2 -= sw2*fs;
  unsigned short* gp = d_stackT + ((size_t)(b*NP + n))*KR + 384;
  gp[c]        = f2bf(a0/(1.f + fabsf(a0)));
  gp[CC + c]   = f2bf(a1/(1.f + fabsf(a1)));
  gp[2*CC + c] = f2bf(a2/(1.f + fabsf(a2)));
}

// ---- MFMA GEMM: 32n x 128o tile, 4 waves (2n x 2o), LDS dbuf, 1 barrier/chunk ----
// layers (aux=1): write bf16 h slab + hTwT only. fc1 (aux=0): write fp32 Out.
__global__ __launch_bounds__(256) void k_mfma(int koff, int K,
                                              const unsigned short* __restrict__ W, size_t wstride,
                                              float* __restrict__ Out,
                                              const float* __restrict__ bias, int bias_stride,
                                              int gelu, int aux) {
  __shared__ unsigned short As[2][32*40];    // [buf][n-row][k] pad 40
  __shared__ unsigned short Bs[2][128*40];   // [buf][o-row][k]
  int b = blockIdx.z;
  int n_base = blockIdx.x*32;
  int tid = threadIdx.x;
  int lane = tid & 63, wid = tid >> 6;
  int wr = wid >> 1, wc = wid & 1;           // n-group, o-group
  int q = lane >> 4, m = lane & 15;

  f32x4 acc[4];
  #pragma unroll
  for (int j = 0; j < 4; j++) acc[j] = (f32x4){0.f,0.f,0.f,0.f};

  const unsigned short* Wb = W + (size_t)b*wstride;
  const unsigned short* Ab = d_stackT + (size_t)b*NP*KR + koff;

#define STAGE(k0, d) { \
    if (tid < 128) { \
      int rowA = tid >> 2; int e8A = (tid & 3)*8; \
      *(uint4*)&As[d][rowA*40 + e8A] = *(const uint4*)(Ab + (size_t)(n_base + rowA)*KR + (k0) + e8A); \
    } \
    _Pragma("unroll") \
    for (int i_ = 0; i_ < 2; i_++) { \
      int idx_ = tid + i_*256; int rowB = idx_ >> 2; int e8B = (idx_ & 3)*8; \
      *(uint4*)&Bs[d][rowB*40 + e8B] = *(const uint4*)(Wb + (size_t)rowB*K + (k0) + e8B); \
    } }

  STAGE(0, 0)
  int cur = 0;
  for (int k0 = 0; k0 < K; k0 += 32) {
    __syncthreads();
    if (k0 + 32 < K) STAGE(k0 + 32, cur ^ 1)
    bf16x8 a = *(const bf16x8*)&As[cur][(wr*16 + m)*40 + q*8];
    #pragma unroll
    for (int ot = 0; ot < 4; ot++) {
      bf16x8 bf = *(const bf16x8*)&Bs[cur][(wc*64 + ot*16 + m)*40 + q*8];
      acc[ot] = __builtin_amdgcn_mfma_f32_16x16x32_bf16(a, bf, acc[ot], 0, 0, 0);
    }
    cur ^= 1;
  }
#undef STAGE

  const float* bp = bias + (size_t)b*bias_stride;
  int nb4 = n_base + wr*16 + q*4;
  float nw4[4];
  #pragma unroll
  for (int r = 0; r < 4; r++)
    nw4[r] = (aux && nb4 + r < NN) ? d_nw[b*NN + nb4 + r] : 0.f;
  #pragma unroll
  for (int ot = 0; ot < 4; ot++) {
    int o = wc*64 + ot*16 + m;
    float bvv = bp[o];
    float vals[4];
    #pragma unroll
    for (int r = 0; r < 4; r++) {
      float v = acc[ot][r] + bvv;
      if (gelu) v = 0.5f*v*(1.f + erff(v*0.70710678118f));
      vals[r] = v;
      if (!aux) Out[((size_t)(b*NP + nb4 + r))*128 + o] = v;
      if (aux && nb4 + r < NN)
        d_stackT[((size_t)(b*NP + nb4 + r))*KR + 256 + o] = f2bf(v);
    }
    if (aux) {
      ushort4 pk;
      pk.x = f2bf(vals[0]*nw4[0]);
      pk.y = f2bf(vals[1]*nw4[1]);
      pk.z = f2bf(vals[2]*nw4[2]);
      pk.w = f2bf(vals[3]*nw4[3]);
      *(ushort4*)&d_hTwT[((size_t)(b*CC + o))*NP + nb4] = pk;
    }
  }
}

// ---- fc2 + residual; u = d_uT [b][n][o2] ----
__global__ __launch_bounds__(256) void k_out(const float* __restrict__ x,
                                             const float* __restrict__ t,
                                             const float* __restrict__ fc2w,
                                             const float* __restrict__ fc2b,
                                             float* __restrict__ out) {
  int tid = blockIdx.x*256 + threadIdx.x;
  if (tid >= BB*NN) return;
  int b = tid / NN, n = tid % NN;
  const float* up = d_uT + ((size_t)(b*NP + n))*FCC;
  float a0 = fc2b[0], a1 = fc2b[1], a2v = fc2b[2];
  #pragma unroll 4
  for (int o2 = 0; o2 < FCC; o2 += 4) {
    float4 uv = *(const float4*)&up[o2];
    a0  += uv.x*fc2w[(o2+0)*3+0] + uv.y*fc2w[(o2+1)*3+0] + uv.z*fc2w[(o2+2)*3+0] + uv.w*fc2w[(o2+3)*3+0];
    a1  += uv.x*fc2w[(o2+0)*3+1] + uv.y*fc2w[(o2+1)*3+1] + uv.z*fc2w[(o2+2)*3+1] + uv.w*fc2w[(o2+3)*3+1];
    a2v += uv.x*fc2w[(o2+0)*3+2] + uv.y*fc2w[(o2+1)*3+2] + uv.z*fc2w[(o2+2)*3+2] + uv.w*fc2w[(o2+3)*3+2];
  }
  float tv = t[tid];
  out[tid*3 + 0] = x[tid*3 + 0] + tv*a0;
  out[tid*3 + 1] = x[tid*3 + 1] + tv*a1;
  out[tid*3 + 2] = x[tid*3 + 2] + tv*a2v;
}

extern "C" void kernel_launch(void* const* d_in, const int* in_sizes, int n_in,
                              void* d_out, int out_size, void* d_ws, size_t ws_size,
                              hipStream_t stream) {
  const float* x     = (const float*)d_in[0];
  const float* t     = (const float*)d_in[1];
  const float* nodes = (const float*)d_in[3];
  const float* nodew = (const float*)d_in[4];
  const int*   edges = (const int*)d_in[5];
  const float* egw   = (const float*)d_in[6];
  const float* modes = (const float*)d_in[7];
  const float* spL   = (const float*)d_in[8];
  const float* fc0w  = (const float*)d_in[9];
  const float* fc0b  = (const float*)d_in[10];
  const float* Wc    = (const float*)d_in[11];
  const float* Ws    = (const float*)d_in[12];
  const float* W0    = (const float*)d_in[13];
  const float* wsw   = (const float*)d_in[14];
  const float* wsb   = (const float*)d_in[15];
  const float* gwsw  = (const float*)d_in[16];
  const float* gwsb  = (const float*)d_in[17];
  const float* fc1w  = (const float*)d_in[18];
  const float* fc1b  = (const float*)d_in[19];
  const float* fc2w  = (const float*)d_in[20];
  const float* fc2b  = (const float*)d_in[21];
  float* out = (float*)d_out;

  unsigned short* d_Amatb_p; hipGetSymbolAddress((void**)&d_Amatb_p, HIP_SYMBOL(d_Amatb));
  unsigned short* d_fc1wb_p; hipGetSymbolAddress((void**)&d_fc1wb_p, HIP_SYMBOL(d_fc1wb));
  float* d_uT_p;    hipGetSymbolAddress((void**)&d_uT_p,    HIP_SYMBOL(d_uT));
  float* d_bias_p;  hipGetSymbolAddress((void**)&d_bias_p,  HIP_SYMBOL(d_bias));

  hipLaunchKernelGGL(k_basis, dim3(BB*NN), dim3(128), 0, stream, nodes, nodew, modes, spL);
  hipLaunchKernelGGL(k_basisT, dim3(628*BB), dim3(256), 0, stream);
  hipLaunchKernelGGL(k_h0, dim3(BB*NN*CC/256), dim3(256), 0, stream, x, t, fc0w, fc0b);
  hipLaunchKernelGGL(k_hT0, dim3(NCHK, BB), dim3(256), 0, stream);
  hipLaunchKernelGGL(k_fc1w, dim3(CC), dim3(FCC), 0, stream, fc1w);
  // CSR build (once; edges constant across layers)
  hipLaunchKernelGGL(k_csr_zero, dim3((BB*NN + 255)/256), dim3(256), 0, stream);
  hipLaunchKernelGGL(k_csr_count, dim3((BB*EE + 255)/256), dim3(256), 0, stream, edges);
  hipLaunchKernelGGL(k_csr_scan, dim3(BB), dim3(1024), 0, stream);
  hipLaunchKernelGGL(k_csr_scatter, dim3((BB*EE + 255)/256), dim3(256), 0, stream, edges, egw);

  for (int l = 0; l < LL; l++) {
    hipLaunchKernelGGL(k_gemm1m, dim3(G1CH, BB), dim3(256), 0, stream);
    hipLaunchKernelGGL(k_reduce1, dim3(256), dim3(256), 0, stream);
    hipLaunchKernelGGL(k_x0, dim3(NCHK, BB), dim3(256), 0, stream);
    hipLaunchKernelGGL(k_spec, dim3(BB*CC, 8), dim3(128), 0, stream, Wc, Ws, l);
    hipLaunchKernelGGL(k_f0, dim3(BB), dim3(CC), 0, stream, W0, wsb, gwsb, l);
    hipLaunchKernelGGL(k_buildAb, dim3(BB*CC), dim3(128), 0, stream, wsw, gwsw, l);
    hipLaunchKernelGGL(k_grad_csr, dim3(BB*NN), dim3(128), 0, stream);
    hipLaunchKernelGGL(k_mfma, dim3(NP/32, 1, BB), dim3(256), 0, stream,
                       0, KR, d_Amatb_p, (size_t)CC*KR, d_uT_p, d_bias_p, CC,
                       (l != LL-1) ? 1 : 0, 1);
  }

  // fc1 via MFMA on the h slab
  hipLaunchKernelGGL(k_mfma, dim3(NP/32, 1, BB), dim3(256), 0, stream,
                     256, CC, d_fc1wb_p, (size_t)0, d_uT_p, fc1b, 0, 1, 0);
  hipLaunchKernelGGL(k_out, dim3((BB*NN + 255)/256), dim3(256), 0, stream, x, t, fc2w, fc2b, out);
}

// Round 12
// 525.841 us; speedup vs baseline: 1.3516x; 1.0726x over previous
//
#include <hip/hip_runtime.h>
#include <math.h>

#define BB 2
#define NN 20000
#define EE 100000
#define DD 3
#define KK 128
#define CC 128
#define LL 3
#define FCC 128
#define GJ (DD*CC)    // 384
#define KR 768        // stacked contraction: 128 bc + 128 bs + 128 h + 384 g
#define NP 20096      // padded N: 157 tiles * 128
#define NCHK 157      // 128-row chunks
#define G1CH 79       // gemm1 split-k chunks (256 n each; last partial, zero-filled)
#define G1N 256

typedef __attribute__((ext_vector_type(8))) short bf16x8;
typedef __attribute__((ext_vector_type(4))) float f32x4;

__device__ inline unsigned short f2bf(float f) {
  unsigned int u = __float_as_uint(f);
  u += 0x7fffu + ((u >> 16) & 1u);
  return (unsigned short)(u >> 16);
}
__device__ inline float bf2f(unsigned short u) {
  return __uint_as_float(((unsigned int)u) << 16);
}

// ---- scratch (device globals) ----
__device__ float d_nw[BB*NN];
__device__ __align__(16) unsigned short d_stackT[(size_t)BB*NP*KR]; // [b][n][r] bf16: 0 bc,128 bs,256 h,384 g
__device__ __align__(16) unsigned short d_bcT[(size_t)BB*KK*NP];    // [b][k][n] bf16, pad-zeroed
__device__ __align__(16) unsigned short d_bsT[(size_t)BB*KK*NP];
__device__ __align__(16) unsigned short d_hTwT[(size_t)BB*CC*NP];   // [b][c][n] bf16 = h*nw, pad-zeroed
__device__ __align__(16) float d_uT[(size_t)BB*NP*FCC];     // fc1 out [b][n][o2] fp32
__device__ __align__(16) unsigned short d_Amatb[BB*CC*KR];  // [b][o][r] bf16
__device__ __align__(16) unsigned short d_fc1wb[FCC*CC];    // [o2][c] bf16
__device__ __align__(16) float d_part[(size_t)BB*4*G1CH*2*64*64];   // [b][quad][chunk][arr][c*64+k]
__device__ float d_xc[BB*CC*KK];
__device__ float d_xs[BB*CC*KK];
__device__ float d_x0p[BB*NCHK*CC];
__device__ float d_fcp[BB*CC*8*KK];   // spec partials [b][o][ch][k]
__device__ float d_fsp[BB*CC*8*KK];
__device__ float d_bias[BB*CC];
// CSR
__device__ int d_cnt[BB*NN];
__device__ int d_cursor[BB*NN];
__device__ int d_off[BB*(NN+1)];
__device__ __align__(16) float4 d_erec[(size_t)BB*EE];      // {dst_bits, w0, w1, w2}

// ---- basis -> stackT bc/bs slabs (bf16) ----
__global__ __launch_bounds__(128) void k_basis(const float* __restrict__ nodes,
                                               const float* __restrict__ nodew,
                                               const float* __restrict__ modes,
                                               const float* __restrict__ spL) {
  int bn = blockIdx.x;            // b*NN + n
  int k  = threadIdx.x;
  int b = bn / NN, n = bn % NN;
  float x0 = nodes[bn*3+0], x1 = nodes[bn*3+1], x2 = nodes[bn*3+2];
  float tmp = x0*modes[k*3+0]*spL[0] + x1*modes[k*3+1]*spL[1] + x2*modes[k*3+2]*spL[2];
  float cv = cosf(tmp), sv = sinf(tmp);
  size_t row = (size_t)(b*NP + n);
  d_stackT[row*KR + k]       = f2bf(cv);
  d_stackT[row*KR + 128 + k] = f2bf(sv);
  if (k == 0) d_nw[bn] = nodew[bn];
}

// ---- transpose stackT bc/bs slabs -> bcT/bsT [k][n] bf16 (once; zero-pads n>=NN) ----
__global__ __launch_bounds__(256) void k_basisT() {
  __shared__ unsigned short t1[32][136];
  __shared__ unsigned short t2[32][136];
  int blk = blockIdx.x;          // 628 * BB
  int nt = blk % 628, b = blk / 628;
  int n0 = nt*32;
  int tid = threadIdx.x;
  int kl = tid & 127, ng = tid >> 7;
  for (int nn = ng; nn < 32; nn += 2) {
    int n = n0 + nn;
    unsigned short cv = 0, sv = 0;
    if (n < NN) {
      const unsigned short* sp = d_stackT + ((size_t)(b*NP + n))*KR;
      cv = sp[kl]; sv = sp[128 + kl];
    }
    t1[nn][kl] = cv;
    t2[nn][kl] = sv;
  }
  __syncthreads();
  int nl = tid & 31, kg = tid >> 5;
  for (int k = kg; k < 128; k += 8) {
    d_bcT[((size_t)(b*KK + k))*NP + n0 + nl] = t1[nl][k];
    d_bsT[((size_t)(b*KK + k))*NP + n0 + nl] = t2[nl][k];
  }
}

// ---- CSR build ----
__global__ __launch_bounds__(256) void k_csr_zero() {
  int tid = blockIdx.x*256 + threadIdx.x;
  if (tid < BB*NN) { d_cnt[tid] = 0; d_cursor[tid] = 0; }
}

__global__ __launch_bounds__(256) void k_csr_count(const int* __restrict__ edges) {
  int e = blockIdx.x*256 + threadIdx.x;
  if (e >= BB*EE) return;
  int b = e / EE;
  int src = edges[e*2 + 0];
  atomicAdd(&d_cnt[b*NN + src], 1);
}

__global__ __launch_bounds__(1024) void k_csr_scan() {
  int b = blockIdx.x;
  __shared__ int sdata[1024];
  __shared__ int carry_s;
  int tid = threadIdx.x;
  if (tid == 0) carry_s = 0;
  __syncthreads();
  for (int chunk = 0; chunk < 20; ++chunk) {
    int i = chunk*1024 + tid;
    int v = (i < NN) ? d_cnt[b*NN + i] : 0;
    sdata[tid] = v;
    __syncthreads();
    for (int s = 1; s < 1024; s <<= 1) {
      int tv = (tid >= s) ? sdata[tid - s] : 0;
      __syncthreads();
      sdata[tid] += tv;
      __syncthreads();
    }
    int excl = carry_s + sdata[tid] - v;
    if (i < NN) d_off[b*(NN+1) + i] = excl;
    __syncthreads();
    if (tid == 1023) carry_s += sdata[1023];
    __syncthreads();
  }
  if (tid == 0) d_off[b*(NN+1) + NN] = carry_s;
}

// ---- scatter: build packed edge records {dst, w0, w1, w2} ----
__global__ __launch_bounds__(256) void k_csr_scatter(const int* __restrict__ edges,
                                                     const float* __restrict__ egw) {
  int e = blockIdx.x*256 + threadIdx.x;
  if (e >= BB*EE) return;
  int b = e / EE;
  int src = edges[e*2 + 0];
  int dst = edges[e*2 + 1];
  int pos = atomicAdd(&d_cursor[b*NN + src], 1);
  d_erec[(size_t)b*EE + d_off[b*(NN+1) + src] + pos] =
      make_float4(__int_as_float(dst), egw[e*3+0], egw[e*3+1], egw[e*3+2]);
}

// ---- fc0 -> stackT h slab (bf16) ----
__global__ __launch_bounds__(256) void k_h0(const float* __restrict__ x,
                                            const float* __restrict__ t,
                                            const float* __restrict__ w,
                                            const float* __restrict__ bias) {
  int tid = blockIdx.x*256 + threadIdx.x;   // (b*NN+n)*CC + c
  int c = tid & 127;
  int bn = tid >> 7;
  int b = bn / NN, n = bn % NN;
  const float* xv = x + bn*3;
  float acc = bias[c] + xv[0]*w[c] + xv[1]*w[CC+c] + xv[2]*w[2*CC+c]
            + t[bn]*w[3*CC+c];
  d_stackT[((size_t)(b*NP + n))*KR + 256 + c] = f2bf(acc);
}

// ---- layer-0 hTwT: stackT h slab (bf16) * nw -> bf16 [c][n], zero-pads ----
__global__ __launch_bounds__(256) void k_hT0() {
  __shared__ unsigned short t[128][136];
  int chunk = blockIdx.x;   // NCHK
  int b = blockIdx.y;
  int n0 = chunk*128;
  int tid = threadIdx.x;
  int cl = tid & 127, ng = tid >> 7;
  for (int nn = ng; nn < 128; nn += 2) {
    int n = n0 + nn;
    unsigned short v = 0;
    if (n < NN) {
      float hv = bf2f(d_stackT[((size_t)(b*NP + n))*KR + 256 + cl]);
      v = f2bf(hv * d_nw[b*NN + n]);
    }
    t[nn][cl] = v;
  }
  __syncthreads();
  int nl = tid & 31, cg = tid >> 5;
  for (int c = cg; c < 128; c += 8)
    for (int nn2 = 0; nn2 < 128; nn2 += 32)
      d_hTwT[((size_t)(b*CC + c))*NP + n0 + nn2 + nl] = t[nn2 + nl][c];
}

// ---- gemm1 MFMA v3: output-split split-K ----
// block = (chunk, quad=ch*2+kh, b): 64c x 64k quadrant over 256 n.
__global__ __launch_bounds__(256) void k_gemm1m() {
  __shared__ unsigned short Ash[2][64*40];
  __shared__ unsigned short Bch[2][64*40];
  __shared__ unsigned short Bsh[2][64*40];
  int chunk = blockIdx.x;   // G1CH
  int quad  = blockIdx.y;   // 0..3
  int b     = blockIdx.z;
  int ch = quad >> 1, kh = quad & 1;
  int tid = threadIdx.x, lane = tid & 63, wid = tid >> 6;
  int q = lane >> 4, m = lane & 15;
  f32x4 accC[4], accS[4];
  #pragma unroll
  for (int j = 0; j < 4; j++) { accC[j] = (f32x4){0.f,0.f,0.f,0.f}; accS[j] = (f32x4){0.f,0.f,0.f,0.f}; }
  const unsigned short* Ab  = d_hTwT + ((size_t)(b*CC + ch*64))*NP;
  const unsigned short* Bcp = d_bcT + ((size_t)(b*KK + kh*64))*NP;
  const unsigned short* Bsp = d_bsT + ((size_t)(b*KK + kh*64))*NP;
  int n0 = chunk*G1N;

#define G1STAGE(nb, d) { \
    int row_ = tid >> 2; int e8_ = (tid & 3)*8; \
    if ((nb) < NP) { \
      *(uint4*)&Ash[d][row_*40 + e8_] = *(const uint4*)(Ab  + (size_t)row_*NP + (nb) + e8_); \
      *(uint4*)&Bch[d][row_*40 + e8_] = *(const uint4*)(Bcp + (size_t)row_*NP + (nb) + e8_); \
      *(uint4*)&Bsh[d][row_*40 + e8_] = *(const uint4*)(Bsp + (size_t)row_*NP + (nb) + e8_); \
    } else { \
      uint4 z_ = make_uint4(0,0,0,0); \
      *(uint4*)&Ash[d][row_*40 + e8_] = z_; \
      *(uint4*)&Bch[d][row_*40 + e8_] = z_; \
      *(uint4*)&Bsh[d][row_*40 + e8_] = z_; \
    } }

  G1STAGE(n0, 0)
  int cur = 0;
  for (int s = 0; s < G1N/32; s++) {
    __syncthreads();
    if (s + 1 < G1N/32) G1STAGE(n0 + (s+1)*32, cur ^ 1)
    bf16x8 a = *(const bf16x8*)&Ash[cur][(wid*16 + m)*40 + q*8];
    #pragma unroll
    for (int kt = 0; kt < 4; kt++) {
      bf16x8 bcf = *(const bf16x8*)&Bch[cur][(kt*16 + m)*40 + q*8];
      accC[kt] = __builtin_amdgcn_mfma_f32_16x16x32_bf16(a, bcf, accC[kt], 0, 0, 0);
      bf16x8 bsf = *(const bf16x8*)&Bsh[cur][(kt*16 + m)*40 + q*8];
      accS[kt] = __builtin_amdgcn_mfma_f32_16x16x32_bf16(a, bsf, accS[kt], 0, 0, 0);
    }
    cur ^= 1;
  }
#undef G1STAGE

  float* base = d_part + ((size_t)(b*4 + quad)*G1CH + chunk)*2*4096;
  #pragma unroll
  for (int kt = 0; kt < 4; kt++)
    #pragma unroll
    for (int r = 0; r < 4; r++) {
      int c = wid*16 + q*4 + r;   // local 0..63
      int k = kt*16 + m;          // local 0..63
      base[c*64 + k]        =  accC[kt][r];
      base[4096 + c*64 + k] = -accS[kt][r];   // xs = -sum
    }
}

// ---- reduce split-k partials -> xc, xs ----
__global__ __launch_bounds__(256) void k_reduce1() {
  int tid = blockIdx.x*256 + threadIdx.x;   // BB*2*128*128 = 65536
  int k = tid & 127;
  int c = (tid >> 7) & 127;
  int arr = (tid >> 14) & 1;
  int b = tid >> 15;
  int ch = c >> 6, cl = c & 63;
  int kh = k >> 6, kl = k & 63;
  int quad = ch*2 + kh;
  const float* p = d_part + ((size_t)(b*4 + quad)*G1CH)*2*4096 + arr*4096 + cl*64 + kl;
  float acc = 0.f;
  for (int t = 0; t < G1CH; t++) acc += p[(size_t)t*2*4096];
  if (arr == 0) d_xc[(b*CC + c)*KK + k] = acc;
  else          d_xs[(b*CC + c)*KK + k] = acc;
}

// ---- x0 partials from hTwT bf16 ----
__global__ __launch_bounds__(256) void k_x0() {
  int chunk = blockIdx.x;   // NCHK
  int b = blockIdx.y;
  int tid = threadIdx.x;
  int c = tid >> 1, half = tid & 1;
  const unsigned short* p = d_hTwT + ((size_t)(b*CC + c))*NP + chunk*128 + half*64;
  float acc = 0.f;
  #pragma unroll
  for (int i = 0; i < 8; i++) {
    ushort4 v0 = *(const ushort4*)&p[i*8];
    ushort4 v1 = *(const ushort4*)&p[i*8 + 4];
    acc += bf2f(v0.x) + bf2f(v0.y) + bf2f(v0.z) + bf2f(v0.w)
         + bf2f(v1.x) + bf2f(v1.y) + bf2f(v1.z) + bf2f(v1.w);
  }
  __shared__ float red[128][2];
  red[c][half] = acc;
  __syncthreads();
  if (half == 0) d_x0p[(b*NCHK + chunk)*CC + c] = red[c][0] + red[c][1];
}

// ---- spectral mix, i-chunked (8 chunks of 16) -> partials ----
__global__ __launch_bounds__(128) void k_spec(const float* __restrict__ Wc,
                                              const float* __restrict__ Ws, int l) {
  int bo = blockIdx.x;          // b*CC + o
  int ch = blockIdx.y;          // 0..7
  int b = bo >> 7;
  int o = bo & 127;
  int k = threadIdx.x;
  int i0 = ch*16;
  const float* wcp = Wc + ((size_t)(l*CC + i0)*CC + o)*KK + k;
  const float* wsp = Ws + ((size_t)(l*CC + i0)*CC + o)*KK + k;
  float fc = 0.f, fs = 0.f;
  #pragma unroll 4
  for (int j = 0; j < 16; j++) {
    int i = i0 + j;
    float xcv = d_xc[(b*CC + i)*KK + k];
    float xsv = d_xs[(b*CC + i)*KK + k];
    float wcv = wcp[(size_t)j*CC*KK];
    float wsv = wsp[(size_t)j*CC*KK];
    fc += xcv*wcv - xsv*wsv;
    fs += xsv*wcv + xcv*wsv;
  }
  d_fcp[((size_t)bo*8 + ch)*KK + k] = fc;
  d_fsp[((size_t)bo*8 + ch)*KK + k] = fs;
}

// ---- f0 + full bias ----
__global__ __launch_bounds__(128) void k_f0(const float* __restrict__ W0,
                                            const float* __restrict__ wsb,
                                            const float* __restrict__ gwsb, int l) {
  int b = blockIdx.x;
  int o = threadIdx.x;
  __shared__ float sx[CC];
  float xv = 0.f;
  for (int p = 0; p < NCHK; p++) xv += d_x0p[(b*NCHK + p)*CC + o];
  sx[o] = xv;
  __syncthreads();
  float acc = 0.f;
  for (int i = 0; i < CC; i++) acc += sx[i]*W0[(l*CC + i)*CC + o];
  d_bias[b*CC + o] = acc + wsb[l*CC + o] + gwsb[l*CC + o];
}

// ---- build A matrix [b][o][r] bf16 (sums spec partials) ----
__global__ __launch_bounds__(128) void k_buildAb(const float* __restrict__ wsw,
                                                 const float* __restrict__ gwsw, int l) {
  int bo = blockIdx.x;
  int b = bo >> 7, o = bo & 127;
  int t = threadIdx.x;
  float fc = 0.f, fs = 0.f;
  #pragma unroll
  for (int ch = 0; ch < 8; ch++) {
    fc += d_fcp[((size_t)bo*8 + ch)*KK + t];
    fs += d_fsp[((size_t)bo*8 + ch)*KK + t];
  }
  unsigned short* dst = d_Amatb + (size_t)bo*KR;
  dst[t]       = f2bf( 2.f*fc);
  dst[128 + t] = f2bf(-2.f*fs);
  dst[256 + t] = f2bf(wsw[(l*CC + o)*CC + t]);
  #pragma unroll
  for (int j = 0; j < 3; j++)
    dst[384 + j*128 + t] = f2bf(gwsw[(size_t)(l*CC + o)*GJ + j*128 + t]);
}

// ---- fc1w transpose to [o2][c] bf16 ----
__global__ __launch_bounds__(128) void k_fc1w(const float* __restrict__ fc1w) {
  int c = blockIdx.x;
  int o2 = threadIdx.x;
  d_fc1wb[o2*CC + c] = f2bf(fc1w[c*FCC + o2]);
}

// ---- CSR edge gradient (bf16 h gathers, 4-unrolled) -> stackT g slab ----
__global__ __launch_bounds__(128) void k_grad_csr() {
  int bn = blockIdx.x;            // b*NN + n
  int b = bn / NN, n = bn % NN;
  int c = threadIdx.x;
  int beg = d_off[b*(NN+1) + n];
  int end = d_off[b*(NN+1) + n + 1];
  const float4* rp = d_erec + (size_t)b*EE;
  const unsigned short* hb = d_stackT + (size_t)b*NP*KR + 256 + c;
  float a0 = 0.f, a1 = 0.f, a2 = 0.f;
  float sw0 = 0.f, sw1 = 0.f, sw2 = 0.f;
  int p = beg;
  for (; p + 4 <= end; p += 4) {
    float4 r1 = rp[p], r2 = rp[p+1], r3 = rp[p+2], r4 = rp[p+3];
    float f1 = bf2f(hb[(size_t)__float_as_int(r1.x)*KR]);
    float f2 = bf2f(hb[(size_t)__float_as_int(r2.x)*KR]);
    float f3 = bf2f(hb[(size_t)__float_as_int(r3.x)*KR]);
    float f4 = bf2f(hb[(size_t)__float_as_int(r4.x)*KR]);
    a0 += r1.y*f1 + r2.y*f2 + r3.y*f3 + r4.y*f4;
    a1 += r1.z*f1 + r2.z*f2 + r3.z*f3 + r4.z*f4;
    a2 += r1.w*f1 + r2.w*f2 + r3.w*f3 + r4.w*f4;
    sw0 += r1.y + r2.y + r3.y + r4.y;
    sw1 += r1.z + r2.z + r3.z + r4.z;
    sw2 += r1.w + r2.w + r3.w + r4.w;
  }
  for (; p < end; ++p) {
    float4 r1 = rp[p];
    float f1 = bf2f(hb[(size_t)__float_as_int(r1.x)*KR]);
    a0 += r1.y*f1; a1 += r1.z*f1; a2 += r1.w*f1;
    sw0 += r1.y; sw1 += r1.z; sw2 += r1.w;
  }
  float fs = bf2f(hb[(size_t)n*KR]);
  a0 -= sw0*fs; a1 -= sw1*fs; a2 -= sw2*fs;
  unsigned short* gp = d_stackT + ((size_t)(b*NP + n))*KR + 384;
  gp[c]        = f2bf(a0/(1.f + fabsf(a0)));
  gp[CC + c]   = f2bf(a1/(1.f + fabsf(a1)));
  gp[2*CC + c] = f2bf(a2/(1.f + fabsf(a2)));
}

// ---- MFMA GEMM: 32n x 128o tile, 4 waves (2n x 2o), LDS dbuf, K-chunk 64 ----
// layers (aux=1): write bf16 h slab + hTwT only. fc1 (aux=0): write fp32 Out.
__global__ __launch_bounds__(256) void k_mfma(int koff, int K,
                                              const unsigned short* __restrict__ W, size_t wstride,
                                              float* __restrict__ Out,
                                              const float* __restrict__ bias, int bias_stride,
                                              int gelu, int aux) {
  __shared__ unsigned short As[2][32*72];    // [buf][n-row][k] pad 72
  __shared__ unsigned short Bs[2][128*72];   // [buf][o-row][k]
  int b = blockIdx.z;
  int n_base = blockIdx.x*32;
  int tid = threadIdx.x;
  int lane = tid & 63, wid = tid >> 6;
  int wr = wid >> 1, wc = wid & 1;           // n-group, o-group
  int q = lane >> 4, m = lane & 15;

  f32x4 acc[4];
  #pragma unroll
  for (int j = 0; j < 4; j++) acc[j] = (f32x4){0.f,0.f,0.f,0.f};

  const unsigned short* Wb = W + (size_t)b*wstride;
  const unsigned short* Ab = d_stackT + (size_t)b*NP*KR + koff;

#define STAGE(k0, d) { \
    { int rowA = tid >> 3; int e8A = (tid & 7)*8; \
      *(uint4*)&As[d][rowA*72 + e8A] = *(const uint4*)(Ab + (size_t)(n_base + rowA)*KR + (k0) + e8A); } \
    _Pragma("unroll") \
    for (int i_ = 0; i_ < 4; i_++) { \
      int idx_ = tid + i_*256; int rowB = idx_ >> 3; int e8B = (idx_ & 7)*8; \
      *(uint4*)&Bs[d][rowB*72 + e8B] = *(const uint4*)(Wb + (size_t)rowB*K + (k0) + e8B); } }

  STAGE(0, 0)
  int cur = 0;
  for (int k0 = 0; k0 < K; k0 += 64) {
    __syncthreads();
    if (k0 + 64 < K) STAGE(k0 + 64, cur ^ 1)
    bf16x8 a0 = *(const bf16x8*)&As[cur][(wr*16 + m)*72 + q*8];
    bf16x8 a1 = *(const bf16x8*)&As[cur][(wr*16 + m)*72 + 32 + q*8];
    #pragma unroll
    for (int ot = 0; ot < 4; ot++) {
      bf16x8 b0 = *(const bf16x8*)&Bs[cur][(wc*64 + ot*16 + m)*72 + q*8];
      acc[ot] = __builtin_amdgcn_mfma_f32_16x16x32_bf16(a0, b0, acc[ot], 0, 0, 0);
      bf16x8 b1 = *(const bf16x8*)&Bs[cur][(wc*64 + ot*16 + m)*72 + 32 + q*8];
      acc[ot] = __builtin_amdgcn_mfma_f32_16x16x32_bf16(a1, b1, acc[ot], 0, 0, 0);
    }
    cur ^= 1;
  }
#undef STAGE

  const float* bp = bias + (size_t)b*bias_stride;
  int nb4 = n_base + wr*16 + q*4;
  float nw4[4];
  #pragma unroll
  for (int r = 0; r < 4; r++)
    nw4[r] = (aux && nb4 + r < NN) ? d_nw[b*NN + nb4 + r] : 0.f;
  #pragma unroll
  for (int ot = 0; ot < 4; ot++) {
    int o = wc*64 + ot*16 + m;
    float bvv = bp[o];
    float vals[4];
    #pragma unroll
    for (int r = 0; r < 4; r++) {
      float v = acc[ot][r] + bvv;
      if (gelu) v = 0.5f*v*(1.f + erff(v*0.70710678118f));
      vals[r] = v;
      if (!aux) Out[((size_t)(b*NP + nb4 + r))*128 + o] = v;
      if (aux && nb4 + r < NN)
        d_stackT[((size_t)(b*NP + nb4 + r))*KR + 256 + o] = f2bf(v);
    }
    if (aux) {
      ushort4 pk;
      pk.x = f2bf(vals[0]*nw4[0]);
      pk.y = f2bf(vals[1]*nw4[1]);
      pk.z = f2bf(vals[2]*nw4[2]);
      pk.w = f2bf(vals[3]*nw4[3]);
      *(ushort4*)&d_hTwT[((size_t)(b*CC + o))*NP + nb4] = pk;
    }
  }
}

// ---- fc2 + residual; u = d_uT [b][n][o2] ----
__global__ __launch_bounds__(256) void k_out(const float* __restrict__ x,
                                             const float* __restrict__ t,
                                             const float* __restrict__ fc2w,
                                             const float* __restrict__ fc2b,
                                             float* __restrict__ out) {
  int tid = blockIdx.x*256 + threadIdx.x;
  if (tid >= BB*NN) return;
  int b = tid / NN, n = tid % NN;
  const float* up = d_uT + ((size_t)(b*NP + n))*FCC;
  float a0 = fc2b[0], a1 = fc2b[1], a2v = fc2b[2];
  #pragma unroll 4
  for (int o2 = 0; o2 < FCC; o2 += 4) {
    float4 uv = *(const float4*)&up[o2];
    a0  += uv.x*fc2w[(o2+0)*3+0] + uv.y*fc2w[(o2+1)*3+0] + uv.z*fc2w[(o2+2)*3+0] + uv.w*fc2w[(o2+3)*3+0];
    a1  += uv.x*fc2w[(o2+0)*3+1] + uv.y*fc2w[(o2+1)*3+1] + uv.z*fc2w[(o2+2)*3+1] + uv.w*fc2w[(o2+3)*3+1];
    a2v += uv.x*fc2w[(o2+0)*3+2] + uv.y*fc2w[(o2+1)*3+2] + uv.z*fc2w[(o2+2)*3+2] + uv.w*fc2w[(o2+3)*3+2];
  }
  float tv = t[tid];
  out[tid*3 + 0] = x[tid*3 + 0] + tv*a0;
  out[tid*3 + 1] = x[tid*3 + 1] + tv*a1;
  out[tid*3 + 2] = x[tid*3 + 2] + tv*a2v;
}

extern "C" void kernel_launch(void* const* d_in, const int* in_sizes, int n_in,
                              void* d_out, int out_size, void* d_ws, size_t ws_size,
                              hipStream_t stream) {
  const float* x     = (const float*)d_in[0];
  const float* t     = (const float*)d_in[1];
  const float* nodes = (const float*)d_in[3];
  const float* nodew = (const float*)d_in[4];
  const int*   edges = (const int*)d_in[5];
  const float* egw   = (const float*)d_in[6];
  const float* modes = (const float*)d_in[7];
  const float* spL   = (const float*)d_in[8];
  const float* fc0w  = (const float*)d_in[9];
  const float* fc0b  = (const float*)d_in[10];
  const float* Wc    = (const float*)d_in[11];
  const float* Ws    = (const float*)d_in[12];
  const float* W0    = (const float*)d_in[13];
  const float* wsw   = (const float*)d_in[14];
  const float* wsb   = (const float*)d_in[15];
  const float* gwsw  = (const float*)d_in[16];
  const float* gwsb  = (const float*)d_in[17];
  const float* fc1w  = (const float*)d_in[18];
  const float* fc1b  = (const float*)d_in[19];
  const float* fc2w  = (const float*)d_in[20];
  const float* fc2b  = (const float*)d_in[21];
  float* out = (float*)d_out;

  unsigned short* d_Amatb_p; hipGetSymbolAddress((void**)&d_Amatb_p, HIP_SYMBOL(d_Amatb));
  unsigned short* d_fc1wb_p; hipGetSymbolAddress((void**)&d_fc1wb_p, HIP_SYMBOL(d_fc1wb));
  float* d_uT_p;    hipGetSymbolAddress((void**)&d_uT_p,    HIP_SYMBOL(d_uT));
  float* d_bias_p;  hipGetSymbolAddress((void**)&d_bias_p,  HIP_SYMBOL(d_bias));

  hipLaunchKernelGGL(k_basis, dim3(BB*NN), dim3(128), 0, stream, nodes, nodew, modes, spL);
  hipLaunchKernelGGL(k_basisT, dim3(628*BB), dim3(256), 0, stream);
  hipLaunchKernelGGL(k_h0, dim3(BB*NN*CC/256), dim3(256), 0, stream, x, t, fc0w, fc0b);
  hipLaunchKernelGGL(k_hT0, dim3(NCHK, BB), dim3(256), 0, stream);
  hipLaunchKernelGGL(k_fc1w, dim3(CC), dim3(FCC), 0, stream, fc1w);
  // CSR build (once; edges constant across layers)
  hipLaunchKernelGGL(k_csr_zero, dim3((BB*NN + 255)/256), dim3(256), 0, stream);
  hipLaunchKernelGGL(k_csr_count, dim3((BB*EE + 255)/256), dim3(256), 0, stream, edges);
  hipLaunchKernelGGL(k_csr_scan, dim3(BB), dim3(1024), 0, stream);
  hipLaunchKernelGGL(k_csr_scatter, dim3((BB*EE + 255)/256), dim3(256), 0, stream, edges, egw);

  for (int l = 0; l < LL; l++) {
    hipLaunchKernelGGL(k_gemm1m, dim3(G1CH, 4, BB), dim3(256), 0, stream);
    hipLaunchKernelGGL(k_reduce1, dim3(256), dim3(256), 0, stream);
    hipLaunchKernelGGL(k_x0, dim3(NCHK, BB), dim3(256), 0, stream);
    hipLaunchKernelGGL(k_spec, dim3(BB*CC, 8), dim3(128), 0, stream, Wc, Ws, l);
    hipLaunchKernelGGL(k_f0, dim3(BB), dim3(CC), 0, stream, W0, wsb, gwsb, l);
    hipLaunchKernelGGL(k_buildAb, dim3(BB*CC), dim3(128), 0, stream, wsw, gwsw, l);
    hipLaunchKernelGGL(k_grad_csr, dim3(BB*NN), dim3(128), 0, stream);
    hipLaunchKernelGGL(k_mfma, dim3(NP/32, 1, BB), dim3(256), 0, stream,
                       0, KR, d_Amatb_p, (size_t)CC*KR, d_uT_p, d_bias_p, CC,
                       (l != LL-1) ? 1 : 0, 1);
  }

  // fc1 via MFMA on the h slab
  hipLaunchKernelGGL(k_mfma, dim3(NP/32, 1, BB), dim3(256), 0, stream,
                     256, CC, d_fc1wb_p, (size_t)0, d_uT_p, fc1b, 0, 1, 0);
  hipLaunchKernelGGL(k_out, dim3((BB*NN + 255)/256), dim3(256), 0, stream, x, t, fc2w, fc2b, out);
}